// Round 7
// baseline (3853.215 us; speedup 1.0000x reference)
//
#include <hip/hip_runtime.h>
#include <hip/hip_bf16.h>
#include <math.h>

// Single-kernel design: the harness template defines exactly one __global__
// kernel with this name; we keep that shape and multiplex all pipeline
// phases through a `phase` argument. All tensors are float32 per the
// reference (setup_inputs is jnp.float32; edge_index int).

__device__ void mm_dev(const float* __restrict__ A, const float* __restrict__ B,
                       float* __restrict__ C, const float* __restrict__ bias,
                       int M, int N, int K, int act, float* a_sh) {
    int m = blockIdx.x;
    if (m >= M) return;
    int t = threadIdx.x;
    for (int k = t; k < K; k += 256) a_sh[k] = A[(size_t)m * K + k];
    __syncthreads();
    for (int c = t; c < N; c += 256) {
        float acc = 0.f;
        const float* bp = B + c;
        for (int k = 0; k < K; k++) acc += a_sh[k] * bp[(size_t)k * N];
        if (bias) acc += bias[c];
        if (act) acc = acc > 0.f ? acc : 0.f;
        C[(size_t)m * N + c] = acc;
    }
    __syncthreads();
}

__device__ void alpha_dev(const float* __restrict__ h, const float* __restrict__ a_s,
                          const float* __restrict__ a_d, float* __restrict__ out_s,
                          float* __restrict__ out_d, float* ss, float* sd) {
    int n = blockIdx.x, t = threadIdx.x;
    for (int e = t; e < 512; e += 256) {
        float hv = h[(size_t)n * 512 + e];
        ss[e] = hv * a_s[e];
        sd[e] = hv * a_d[e];
    }
    __syncthreads();
    int g = t >> 6, u = t & 63, base = g * 128;
    ss[base + u] += ss[base + 64 + u];
    sd[base + u] += sd[base + 64 + u];
    __syncthreads();
    for (int s = 32; s >= 1; s >>= 1) {
        if (u < s) {
            ss[base + u] += ss[base + u + s];
            sd[base + u] += sd[base + u + s];
        }
        __syncthreads();
    }
    if (u == 0) { out_s[n * 4 + g] = ss[base]; out_d[n * 4 + g] = sd[base]; }
    __syncthreads();
}

__device__ void agg_dev(const int* __restrict__ rowptr, const int* __restrict__ col,
                        const float* __restrict__ asrc, const float* __restrict__ adst,
                        const float* __restrict__ h, const float* __restrict__ bias,
                        float* __restrict__ out, int elu) {
    int n = blockIdx.x;
    int w = threadIdx.x >> 6, l = threadIdx.x & 63;
    int beg = rowptr[n], end = rowptr[n + 1];
    float ad = adst[n * 4 + w];
    float m = -1e30f, ssum = 0.f, acc0 = 0.f, acc1 = 0.f;
    for (int j = beg; j < end; ++j) {
        int s = col[j];
        float e = asrc[s * 4 + w] + ad;
        e = e > 0.f ? e : 0.2f * e;                    // leaky_relu(0.2)
        float mn = e > m ? e : m;
        float scale = expf(m - mn);                    // first iter: 0
        float p = expf(e - mn);
        const float* hp = h + (size_t)s * 512 + w * 128 + 2 * l;
        float h0 = hp[0], h1 = hp[1];
        ssum = ssum * scale + p;
        acc0 = acc0 * scale + p * h0;
        acc1 = acc1 * scale + p * h1;
        m = mn;
    }
    float inv = 1.f / (ssum + 1e-16f);
    int cbase = w * 128 + 2 * l;
    float v0 = acc0 * inv + bias[cbase];
    float v1 = acc1 * inv + bias[cbase + 1];
    if (elu) {
        v0 = v0 > 0.f ? v0 : expm1f(v0);
        v1 = v1 > 0.f ? v1 : expm1f(v1);
    }
    float* op = out + (size_t)n * 512 + cbase;
    op[0] = v0;
    op[1] = v1;
}

__global__ __launch_bounds__(256) void BaselineGAT_41764261987077_kernel(
    int phase, int aux,
    const float* x, const int* ei,
    const float* W1, const float* as1, const float* ad1, const float* b1,
    const float* W2, const float* as2, const float* ad2, const float* b2,
    const float* Wc1, const float* bc1, const float* Wc2, const float* bc2,
    float* out,
    float* hA, float* hB, float* asr, float* ads,
    int* flag, int* cnt, int* tmp, int* bsum, int* boff,
    int* rowptr, int* cursor, int* col,
    int NODES, int E, int nblk)
{
    __shared__ float smf[1312];
    __shared__ int smi[257];
    const int t = threadIdx.x;
    const int gid = blockIdx.x * 256 + t;
    const int EN = E + NODES;

    switch (phase) {
    case 100: {   // tracer / sentinel paint of out
        float v = (aux == 0) ? 0.25f : 1000.0f;
        if (gid < NODES * 10) out[gid] = v;
    } break;
    case 0: {     // edge dtype detect: int64 -> odd int32 slots are 0
        if (t == 0) smi[256] = 0;
        __syncthreads();
        for (int j = t; j < 1024; j += 256)
            if (ei[2 * j + 1] != 0) atomicAdd(&smi[256], 1);
        __syncthreads();
        if (t == 0) flag[0] = (smi[256] < 16) ? 2 : 1;
    } break;
    case 1: {     // zero cnt
        if (gid < NODES) cnt[gid] = 0;
    } break;
    case 2: {     // histogram of dst (+ self loops)
        if (gid >= EN) return;
        int step = flag[0];
        int d;
        if (gid < E) {
            d = ei[(size_t)(E + gid) * step];
            if ((unsigned)d >= (unsigned)NODES) d = 0;
        } else d = gid - E;
        atomicAdd(&cnt[d], 1);
    } break;
    case 3: {     // block-local inclusive scan
        smi[t] = (gid < NODES) ? cnt[gid] : 0;
        __syncthreads();
        for (int o = 1; o < 256; o <<= 1) {
            int add = (t >= o) ? smi[t - o] : 0;
            __syncthreads();
            smi[t] += add;
            __syncthreads();
        }
        if (gid < NODES) tmp[gid] = smi[t];
        if (t == 255) bsum[blockIdx.x] = smi[255];
    } break;
    case 4: {     // serial exclusive scan of block sums
        if (blockIdx.x == 0 && t == 0) {
            int ex = 0;
            for (int b = 0; b < nblk; b++) { boff[b] = ex; ex += bsum[b]; }
        }
    } break;
    case 5: {     // rowptr + cursor
        if (gid >= NODES) return;
        int incl = tmp[gid] + boff[blockIdx.x];
        rowptr[gid + 1] = incl;
        cursor[gid] = incl - cnt[gid];
        if (gid == 0) rowptr[0] = 0;
    } break;
    case 6: {     // fill CSR col
        if (gid >= EN) return;
        int step = flag[0];
        int d, s;
        if (gid < E) {
            s = ei[(size_t)gid * step];
            d = ei[(size_t)(E + gid) * step];
            if ((unsigned)s >= (unsigned)NODES) s = 0;
            if ((unsigned)d >= (unsigned)NODES) d = 0;
        } else { d = gid - E; s = d; }
        int pos = atomicAdd(&cursor[d], 1);
        col[pos] = s;
    } break;
    case 7:  mm_dev(x,  W1,  hA, nullptr, NODES, 512, 336, 0, smf); break;
    case 8:  alpha_dev(hA, as1, ad1, asr, ads, smf, smf + 512);     break;
    case 9:  agg_dev(rowptr, col, asr, ads, hA, b1, hB, 1);         break;
    case 10: mm_dev(hB, W2,  hA, nullptr, NODES, 512, 512, 0, smf); break;
    case 11: alpha_dev(hA, as2, ad2, asr, ads, smf, smf + 512);     break;
    case 12: agg_dev(rowptr, col, asr, ads, hA, b2, hB, 0);         break;
    case 13: mm_dev(hB, Wc1, hA, bc1,    NODES, 128, 512, 1, smf);  break;
    case 14: {    // logits = z(=hA)[N,128] @ Wc2[128,10] + bc2
        for (int i = t; i < 1280; i += 256) smf[i] = Wc2[i];
        if (t < 10) smf[1280 + t] = bc2[t];
        __syncthreads();
        int n = gid;
        if (n >= NODES) return;
        float acc[10];
        for (int c = 0; c < 10; c++) acc[c] = smf[1280 + c];
        const float* zp = hA + (size_t)n * 128;
        for (int k = 0; k < 128; k++) {
            float f = zp[k];
            const float* wr = &smf[k * 10];
            for (int c = 0; c < 10; c++) acc[c] += f * wr[c];
        }
        float* op = out + (size_t)n * 10;
        for (int c = 0; c < 10; c++) op[c] = acc[c];
    } break;
    }
}

extern "C" void kernel_launch(void* const* d_in, const int* in_sizes, int n_in,
                              void* d_out, int out_size, void* d_ws, size_t ws_size,
                              hipStream_t stream) {
    const float* x   = (const float*)d_in[0];
    const int*   ei  = (const int*)d_in[1];
    const float* W1  = (const float*)d_in[2];
    const float* as1 = (const float*)d_in[3];
    const float* ad1 = (const float*)d_in[4];
    const float* b1  = (const float*)d_in[5];
    const float* W2  = (const float*)d_in[6];
    const float* as2 = (const float*)d_in[7];
    const float* ad2 = (const float*)d_in[8];
    const float* b2  = (const float*)d_in[9];
    const float* Wc1 = (const float*)d_in[10];
    const float* bc1 = (const float*)d_in[11];
    const float* Wc2 = (const float*)d_in[12];
    const float* bc2 = (const float*)d_in[13];

    const int NODES = in_sizes[0] / 336;   // 50000
    const int E     = in_sizes[1] / 2;     // 500000

    char* ws = (char*)d_ws;
    size_t off = 0;
    auto alloc = [&](size_t b) -> char* {
        char* p = ws + off; off = (off + b + 255) & ~(size_t)255; return p;
    };
    float* hA   = (float*)alloc((size_t)NODES * 512 * 4);
    float* hB   = (float*)alloc((size_t)NODES * 512 * 4);
    float* asr  = (float*)alloc((size_t)NODES * 4 * 4);
    float* ads  = (float*)alloc((size_t)NODES * 4 * 4);
    int* flag   = (int*)alloc(256);
    int* cnt    = (int*)alloc((size_t)NODES * 4);
    int* tmp    = (int*)alloc((size_t)NODES * 4);
    int* bsum   = (int*)alloc(4096);
    int* boff   = (int*)alloc(4096);
    int* rowptr = (int*)alloc((size_t)(NODES + 1) * 4);
    int* cursor = (int*)alloc((size_t)NODES * 4);
    int* col    = (int*)alloc((size_t)(E + NODES) * 4);

    const int nblk  = (NODES + 255) / 256;
    const int eblk  = (E + NODES + 255) / 256;
    const int oblk  = (out_size + 255) / 256;

    auto L = [&](int phase, int aux, int grid) {
        BaselineGAT_41764261987077_kernel<<<grid, 256, 0, stream>>>(
            phase, aux, x, ei, W1, as1, ad1, b1, W2, as2, ad2, b2,
            Wc1, bc1, Wc2, bc2, (float*)d_out,
            hA, hB, asr, ads, flag, cnt, tmp, bsum, boff,
            rowptr, cursor, col, NODES, E, nblk);
    };

    // tracer paint: if the pipeline dies midway, absmax shifts off 1.625 exactly
    L(100, 0, oblk);
    if (n_in < 14 || off > ws_size) { L(100, 1, oblk); return; }

    // CSR build
    L(0, 0, 1);
    L(1, 0, nblk);
    L(2, 0, eblk);
    L(3, 0, nblk);
    L(4, 0, 1);
    L(5, 0, nblk);
    L(6, 0, eblk);
    // layer 1
    L(7, 0, NODES);
    L(8, 0, NODES);
    L(9, 0, NODES);
    // layer 2
    L(10, 0, NODES);
    L(11, 0, NODES);
    L(12, 0, NODES);
    // classifier
    L(13, 0, NODES);
    L(14, 0, nblk);
}

// Round 8
// 1953.659 us; speedup vs baseline: 1.9723x; 1.9723x over previous
//
#include <hip/hip_runtime.h>
#include <math.h>

typedef unsigned short u16;
typedef unsigned int u32;
typedef short short8 __attribute__((ext_vector_type(8)));
typedef __bf16 bf16x8 __attribute__((ext_vector_type(8)));
typedef float f32x4 __attribute__((ext_vector_type(4)));

__device__ __forceinline__ u16 f2b(float f) {
    union { float f; u32 i; } v; v.f = f;
    u32 i = v.i;
    u32 r = (i + 0x7fffu + ((i >> 16) & 1u)) >> 16;   // RNE fp32 -> bf16
    return (u16)r;
}
__device__ __forceinline__ u32 pack2(u16 a, u16 b) { return (u32)a | ((u32)b << 16); }

// ---------- device helpers (all phases live in the ONE named kernel) ----------

__device__ void alpha_dev(const float* __restrict__ h, const float* __restrict__ a_s,
                          const float* __restrict__ a_d, float* __restrict__ out_s,
                          float* __restrict__ out_d, float* ss, float* sd) {
    int n = blockIdx.x, t = threadIdx.x;
    for (int e = t; e < 512; e += 256) {
        float hv = h[(size_t)n * 512 + e];
        ss[e] = hv * a_s[e];
        sd[e] = hv * a_d[e];
    }
    __syncthreads();
    int g = t >> 6, u = t & 63, base = g * 128;
    ss[base + u] += ss[base + 64 + u];
    sd[base + u] += sd[base + 64 + u];
    __syncthreads();
    for (int s = 32; s >= 1; s >>= 1) {
        if (u < s) {
            ss[base + u] += ss[base + u + s];
            sd[base + u] += sd[base + u + s];
        }
        __syncthreads();
    }
    if (u == 0) { out_s[n * 4 + g] = ss[base]; out_d[n * 4 + g] = sd[base]; }
    __syncthreads();
}

// segment softmax + aggregate; h fp32 gather; OUTPUT bf16 (feeds next GEMM).
__device__ void agg_dev(const int* __restrict__ rowptr, const int* __restrict__ col,
                        const float* __restrict__ asrc, const float* __restrict__ adst,
                        const float* __restrict__ h, const float* __restrict__ bias,
                        u16* __restrict__ outb, int elu) {
    int n = blockIdx.x;
    int w = threadIdx.x >> 6, l = threadIdx.x & 63;
    int beg = rowptr[n], end = rowptr[n + 1];
    float ad = adst[n * 4 + w];
    float m = -1e30f, ssum = 0.f, acc0 = 0.f, acc1 = 0.f;
    for (int j = beg; j < end; ++j) {
        int s = col[j];
        float e = asrc[s * 4 + w] + ad;
        e = e > 0.f ? e : 0.2f * e;                    // leaky_relu(0.2)
        float mn = e > m ? e : m;
        float scale = expf(m - mn);                    // first iter: 0
        float p = expf(e - mn);
        const float* hp = h + (size_t)s * 512 + w * 128 + 2 * l;
        float h0 = hp[0], h1 = hp[1];
        ssum = ssum * scale + p;
        acc0 = acc0 * scale + p * h0;
        acc1 = acc1 * scale + p * h1;
        m = mn;
    }
    float inv = 1.f / (ssum + 1e-16f);
    int cbase = w * 128 + 2 * l;
    float v0 = acc0 * inv + bias[cbase];
    float v1 = acc1 * inv + bias[cbase + 1];
    if (elu) {
        v0 = v0 > 0.f ? v0 : expm1f(v0);
        v1 = v1 > 0.f ? v1 : expm1f(v1);
    }
    *(u32*)(outb + (size_t)n * 512 + cbase) = pack2(f2b(v0), f2b(v1));
}

// MFMA GEMM: C fp32[M,N] = A bf16[M,K] @ Bt bf16[N,K]^T (+bias, optional relu).
// 128x128 tile, 4 waves 2x2, register-staged LDS, K multiple of 32 (pre-padded).
__device__ void gemm_dev(const u16* __restrict__ A, const u16* __restrict__ Bt,
                         float* __restrict__ C, const float* __restrict__ bias,
                         int M, int N, int K, int act, u16* As, u16* Bs) {
    const int t = threadIdx.x;
    const int l = t & 63, w = t >> 6;
    const int m0 = blockIdx.x * 128, n0 = blockIdx.y * 128;
    const int sr = t >> 2;             // 0..63
    const int sc = (t & 3) * 8;        // 16B chunks
    const int wm = (w >> 1) * 64, wn = (w & 1) * 64;

    const int rA0 = min(m0 + sr, M - 1);
    const int rA1 = min(m0 + sr + 64, M - 1);
    const int rB0 = min(n0 + sr, N - 1);
    const int rB1 = min(n0 + sr + 64, N - 1);

    f32x4 acc[4][4];
    f32x4 z4 = {0.f, 0.f, 0.f, 0.f};
#pragma unroll
    for (int i = 0; i < 4; i++)
#pragma unroll
        for (int j = 0; j < 4; j++) acc[i][j] = z4;

    for (int k0 = 0; k0 < K; k0 += 32) {
        short8 a0 = *(const short8*)(A + (size_t)rA0 * K + k0 + sc);
        short8 a1 = *(const short8*)(A + (size_t)rA1 * K + k0 + sc);
        short8 b0 = *(const short8*)(Bt + (size_t)rB0 * K + k0 + sc);
        short8 b1 = *(const short8*)(Bt + (size_t)rB1 * K + k0 + sc);
        __syncthreads();   // prior LDS reads done
        *(short8*)(As + sr * 32 + sc) = a0;
        *(short8*)(As + (sr + 64) * 32 + sc) = a1;
        *(short8*)(Bs + sr * 32 + sc) = b0;
        *(short8*)(Bs + (sr + 64) * 32 + sc) = b1;
        __syncthreads();

        bf16x8 af[4], bfr[4];
#pragma unroll
        for (int i = 0; i < 4; i++) {
            af[i]  = *(const bf16x8*)(As + (wm + i * 16 + (l & 15)) * 32 + (l >> 4) * 8);
            bfr[i] = *(const bf16x8*)(Bs + (wn + i * 16 + (l & 15)) * 32 + (l >> 4) * 8);
        }
#pragma unroll
        for (int i = 0; i < 4; i++)
#pragma unroll
            for (int j = 0; j < 4; j++)
                acc[i][j] = __builtin_amdgcn_mfma_f32_16x16x32_bf16(af[i], bfr[j], acc[i][j], 0, 0, 0);
    }

#pragma unroll
    for (int i = 0; i < 4; i++) {
        int rbase = m0 + wm + i * 16 + (l >> 4) * 4;
#pragma unroll
        for (int j = 0; j < 4; j++) {
            int c = n0 + wn + j * 16 + (l & 15);
            float bv = bias ? bias[c] : 0.f;
#pragma unroll
            for (int r = 0; r < 4; r++) {
                int row = rbase + r;
                if (row < M) {
                    float v = acc[i][j][r] + bv;
                    if (act) v = v > 0.f ? v : 0.f;
                    C[(size_t)row * N + c] = v;
                }
            }
        }
    }
}

__global__ __launch_bounds__(256) void BaselineGAT_41764261987077_kernel(
    int phase, int aux,
    const float* x, const int* ei,
    const float* W1, const float* as1, const float* ad1, const float* b1,
    const float* W2, const float* as2, const float* ad2, const float* b2,
    const float* Wc1, const float* bc1, const float* Wc2, const float* bc2,
    float* out,
    float* hA, u16* hbB, float* asr, float* ads,
    u16* xb, u16* w1t, u16* w2t, u16* wc1t,
    int* flag, int* cnt, int* tmp, int* bsum, int* boff,
    int* rowptr, int* cursor, int* col,
    const u16* gA, const u16* gB, float* gC, const float* gBias,
    int gM, int gN, int gK, int gAct,
    int NODES, int E, int nblk)
{
    __shared__ float smf[1312];
    __shared__ int smi[257];
    __shared__ u16 As[128 * 32];
    __shared__ u16 Bs[128 * 32];
    const int t = threadIdx.x;
    const int gid = blockIdx.x * 256 + t;
    const int EN = E + NODES;

    switch (phase) {
    case 100: {   // tracer / ws-sentinel paint
        float v = (aux == 0) ? 0.25f : 1000.0f;
        if (gid < NODES * 10) out[gid] = v;
    } break;
    case 0: {     // edge dtype detect (int64 -> odd int32 slots all zero)
        if (t == 0) smi[256] = 0;
        __syncthreads();
        for (int j = t; j < 1024; j += 256)
            if (ei[2 * j + 1] != 0) atomicAdd(&smi[256], 1);
        __syncthreads();
        if (t == 0) flag[0] = (smi[256] < 16) ? 2 : 1;
    } break;
    case 1: { if (gid < NODES) cnt[gid] = 0; } break;
    case 2: {     // histogram of dst (+self loops)
        if (gid >= EN) return;
        int step = flag[0];
        int d;
        if (gid < E) {
            d = ei[(size_t)(E + gid) * step];
            if ((unsigned)d >= (unsigned)NODES) d = 0;
        } else d = gid - E;
        atomicAdd(&cnt[d], 1);
    } break;
    case 3: {     // block-local inclusive scan
        smi[t] = (gid < NODES) ? cnt[gid] : 0;
        __syncthreads();
        for (int o = 1; o < 256; o <<= 1) {
            int add = (t >= o) ? smi[t - o] : 0;
            __syncthreads();
            smi[t] += add;
            __syncthreads();
        }
        if (gid < NODES) tmp[gid] = smi[t];
        if (t == 255) bsum[blockIdx.x] = smi[255];
    } break;
    case 4: {
        if (blockIdx.x == 0 && t == 0) {
            int ex = 0;
            for (int b = 0; b < nblk; b++) { boff[b] = ex; ex += bsum[b]; }
        }
    } break;
    case 5: {
        if (gid >= NODES) return;
        int incl = tmp[gid] + boff[blockIdx.x];
        rowptr[gid + 1] = incl;
        cursor[gid] = incl - cnt[gid];
        if (gid == 0) rowptr[0] = 0;
    } break;
    case 6: {
        if (gid >= EN) return;
        int step = flag[0];
        int d, s;
        if (gid < E) {
            s = ei[(size_t)gid * step];
            d = ei[(size_t)(E + gid) * step];
            if ((unsigned)s >= (unsigned)NODES) s = 0;
            if ((unsigned)d >= (unsigned)NODES) d = 0;
        } else { d = gid - E; s = d; }
        int pos = atomicAdd(&cursor[d], 1);
        col[pos] = s;
    } break;
    case 20: {    // x fp32 [N,336] -> xb bf16 [N,352] zero-padded
        if (gid >= NODES * 352) return;
        int n = gid / 352, k = gid - n * 352;
        xb[gid] = (k < 336) ? f2b(x[(size_t)n * 336 + k]) : (u16)0;
    } break;
    case 21: {    // W1 [336,512] -> w1t bf16 [512,352] (transpose + pad)
        if (gid >= 512 * 352) return;
        int n = gid / 352, k = gid - n * 352;
        w1t[gid] = (k < 336) ? f2b(W1[(size_t)k * 512 + n]) : (u16)0;
    } break;
    case 22: {    // W2 [512,512] -> w2t bf16 [512,512] (transpose)
        if (gid >= 512 * 512) return;
        int n = gid >> 9, k = gid & 511;
        w2t[gid] = f2b(W2[(size_t)k * 512 + n]);
    } break;
    case 23: {    // Wc1 [512,128] -> wc1t bf16 [128,512] (transpose)
        if (gid >= 128 * 512) return;
        int n = gid >> 9, k = gid & 511;
        wc1t[gid] = f2b(Wc1[(size_t)k * 128 + n]);
    } break;
    case 30: gemm_dev(gA, gB, gC, gBias, gM, gN, gK, gAct, As, Bs); break;
    case 8:  alpha_dev(hA, as1, ad1, asr, ads, smf, smf + 512); break;
    case 11: alpha_dev(hA, as2, ad2, asr, ads, smf, smf + 512); break;
    case 31: agg_dev(rowptr, col, asr, ads, hA, gBias, hbB, aux); break;
    case 14: {    // logits = z(=gC)[N,128] @ Wc2[128,10] + bc2
        for (int i = t; i < 1280; i += 256) smf[i] = Wc2[i];
        if (t < 10) smf[1280 + t] = bc2[t];
        __syncthreads();
        int n = gid;
        if (n >= NODES) return;
        float acc[10];
        for (int c = 0; c < 10; c++) acc[c] = smf[1280 + c];
        const float* zp = gC + (size_t)n * 128;
        for (int k = 0; k < 128; k++) {
            float f = zp[k];
            const float* wr = &smf[k * 10];
            for (int c = 0; c < 10; c++) acc[c] += f * wr[c];
        }
        float* op = out + (size_t)n * 10;
        for (int c = 0; c < 10; c++) op[c] = acc[c];
    } break;
    }
}

extern "C" void kernel_launch(void* const* d_in, const int* in_sizes, int n_in,
                              void* d_out, int out_size, void* d_ws, size_t ws_size,
                              hipStream_t stream) {
    const float* x   = (const float*)d_in[0];
    const int*   ei  = (const int*)d_in[1];
    const float* W1  = (const float*)d_in[2];
    const float* as1 = (const float*)d_in[3];
    const float* ad1 = (const float*)d_in[4];
    const float* b1  = (const float*)d_in[5];
    const float* W2  = (const float*)d_in[6];
    const float* as2 = (const float*)d_in[7];
    const float* ad2 = (const float*)d_in[8];
    const float* b2  = (const float*)d_in[9];
    const float* Wc1 = (const float*)d_in[10];
    const float* bc1 = (const float*)d_in[11];
    const float* Wc2 = (const float*)d_in[12];
    const float* bc2 = (const float*)d_in[13];

    const int NODES = in_sizes[0] / 336;   // 50000
    const int E     = in_sizes[1] / 2;     // 500000

    char* ws = (char*)d_ws;
    size_t off = 0;
    auto alloc = [&](size_t b) -> char* {
        char* p = ws + off; off = (off + b + 255) & ~(size_t)255; return p;
    };
    u16*   xb   = (u16*)alloc((size_t)NODES * 352 * 2);   // reused as z (fp32) later
    float* hA   = (float*)alloc((size_t)NODES * 512 * 4);
    u16*   hbB  = (u16*)alloc((size_t)NODES * 512 * 2);
    float* asr  = (float*)alloc((size_t)NODES * 4 * 4);
    float* ads  = (float*)alloc((size_t)NODES * 4 * 4);
    u16*   w1t  = (u16*)alloc((size_t)512 * 352 * 2);
    u16*   w2t  = (u16*)alloc((size_t)512 * 512 * 2);
    u16*   wc1t = (u16*)alloc((size_t)128 * 512 * 2);
    int* flag   = (int*)alloc(256);
    int* cnt    = (int*)alloc((size_t)NODES * 4);
    int* tmp    = (int*)alloc((size_t)NODES * 4);
    int* bsum   = (int*)alloc(4096);
    int* boff   = (int*)alloc(4096);
    int* rowptr = (int*)alloc((size_t)(NODES + 1) * 4);
    int* cursor = (int*)alloc((size_t)NODES * 4);
    int* col    = (int*)alloc((size_t)(E + NODES) * 4);
    float* z    = (float*)xb;   // xb dead after GEMM1; 25.6 MB <= 35.2 MB

    const int nblk = (NODES + 255) / 256;
    const int eblk = (E + NODES + 255) / 256;
    const int oblk = (out_size + 255) / 256;
    const int mt   = (NODES + 127) / 128;

    auto L = [&](int phase, int aux, dim3 grid,
                 const u16* gA = nullptr, const u16* gB = nullptr,
                 float* gC = nullptr, const float* gBias = nullptr,
                 int gM = 0, int gN = 0, int gK = 0, int gAct = 0) {
        BaselineGAT_41764261987077_kernel<<<grid, 256, 0, stream>>>(
            phase, aux, x, ei, W1, as1, ad1, b1, W2, as2, ad2, b2,
            Wc1, bc1, Wc2, bc2, (float*)d_out,
            hA, hbB, asr, ads, xb, w1t, w2t, wc1t,
            flag, cnt, tmp, bsum, boff, rowptr, cursor, col,
            gA, gB, gC, gBias, gM, gN, gK, gAct,
            NODES, E, nblk);
    };

    L(100, 0, oblk);                                    // tracer paint
    if (n_in < 14 || off > ws_size) { L(100, 1, oblk); return; }

    // CSR build
    L(0, 0, 1); L(1, 0, nblk); L(2, 0, eblk); L(3, 0, nblk);
    L(4, 0, 1); L(5, 0, nblk); L(6, 0, eblk);

    // bf16 conversions
    L(20, 0, (NODES * 352 + 255) / 256);
    L(21, 0, (512 * 352 + 255) / 256);
    L(22, 0, (512 * 512 + 255) / 256);
    L(23, 0, (128 * 512 + 255) / 256);

    // layer 1: h1 = xb @ w1t^T  (fp32 out), alpha, agg(elu) -> hbB bf16
    L(30, 0, dim3(mt, 4), xb, w1t, hA, nullptr, NODES, 512, 352, 0);
    L(8, 0, NODES);
    L(31, 1, NODES, nullptr, nullptr, nullptr, b1);

    // layer 2
    L(30, 0, dim3(mt, 4), hbB, w2t, hA, nullptr, NODES, 512, 512, 0);
    L(11, 0, NODES);
    L(31, 0, NODES, nullptr, nullptr, nullptr, b2);

    // classifier: z = relu(hbB @ wc1t^T + bc1), logits = z @ Wc2 + bc2
    L(30, 0, dim3(mt, 1), hbB, wc1t, z, bc1, NODES, 128, 512, 1);
    L(14, 0, nblk, nullptr, nullptr, z);
}

// Round 9
// 1449.730 us; speedup vs baseline: 2.6579x; 1.3476x over previous
//
#include <hip/hip_runtime.h>
#include <math.h>

typedef unsigned short u16;
typedef unsigned int u32;
typedef short short8 __attribute__((ext_vector_type(8)));
typedef __bf16 bf16x8 __attribute__((ext_vector_type(8)));
typedef float f32x4 __attribute__((ext_vector_type(4)));

__device__ __forceinline__ float b2f(u16 u) {
    union { u32 i; float f; } v; v.i = ((u32)u) << 16; return v.f;
}
__device__ __forceinline__ float b2f_lo(u32 q) {
    union { u32 i; float f; } v; v.i = q << 16; return v.f;
}
__device__ __forceinline__ float b2f_hi(u32 q) {
    union { u32 i; float f; } v; v.i = q & 0xffff0000u; return v.f;
}
__device__ __forceinline__ u16 f2b(float f) {
    union { float f; u32 i; } v; v.f = f;
    u32 i = v.i;
    u32 r = (i + 0x7fffu + ((i >> 16) & 1u)) >> 16;   // RNE fp32 -> bf16
    return (u16)r;
}
__device__ __forceinline__ u32 pack2(u16 a, u16 b) { return (u32)a | ((u32)b << 16); }

// ---------- device helpers (all phases live in the ONE named kernel) ----------

// alpha dot products; h is bf16 now
__device__ void alpha_dev(const u16* __restrict__ h, const float* __restrict__ a_s,
                          const float* __restrict__ a_d, float* __restrict__ out_s,
                          float* __restrict__ out_d, float* ss, float* sd) {
    int n = blockIdx.x, t = threadIdx.x;
    for (int e = t; e < 512; e += 256) {
        float hv = b2f(h[(size_t)n * 512 + e]);
        ss[e] = hv * a_s[e];
        sd[e] = hv * a_d[e];
    }
    __syncthreads();
    int g = t >> 6, u = t & 63, base = g * 128;
    ss[base + u] += ss[base + 64 + u];
    sd[base + u] += sd[base + 64 + u];
    __syncthreads();
    for (int s = 32; s >= 1; s >>= 1) {
        if (u < s) {
            ss[base + u] += ss[base + u + s];
            sd[base + u] += sd[base + u + s];
        }
        __syncthreads();
    }
    if (u == 0) { out_s[n * 4 + g] = ss[base]; out_d[n * 4 + g] = sd[base]; }
    __syncthreads();
}

// segment softmax + aggregate. Wave-per-node (4 nodes/block); lane l owns
// channels 8l..8l+7 (head = l>>4); one bf16x8 (16B) gather per lane per edge.
// Software-pipelined col/asrc prefetch. Output bf16.
__device__ void agg_dev(const int* __restrict__ rowptr, const int* __restrict__ col,
                        const float* __restrict__ asrc, const float* __restrict__ adst,
                        const u16* __restrict__ hb, const float* __restrict__ bias,
                        u16* __restrict__ outb, int elu, int NODES) {
    int w = threadIdx.x >> 6, l = threadIdx.x & 63;
    int n = blockIdx.x * 4 + w;
    if (n >= NODES) return;
    int hd = l >> 4;
    int beg = rowptr[n], end = rowptr[n + 1];
    float ad = adst[n * 4 + hd];
    float m = -1e30f, ssum = 0.f;
    float acc[8];
#pragma unroll
    for (int c = 0; c < 8; c++) acc[c] = 0.f;

    int sj = col[beg];                       // >=1 edge guaranteed (self loop)
    float av = asrc[sj * 4 + hd];
    for (int j = beg; j < end; ++j) {
        int s = sj;
        float a = av;
        if (j + 1 < end) {                   // prefetch next edge
            sj = col[j + 1];
            av = asrc[sj * 4 + hd];
        }
        const u32* hp = (const u32*)(hb + (size_t)s * 512 + 8 * l);
        u32 q0 = hp[0], q1 = hp[1], q2 = hp[2], q3 = hp[3];
        float e = a + ad;
        e = e > 0.f ? e : 0.2f * e;          // leaky_relu(0.2)
        float mn = e > m ? e : m;
        float scale = __expf(m - mn);        // first iter: 0
        float p = __expf(e - mn);
        ssum = ssum * scale + p;
        acc[0] = acc[0] * scale + p * b2f_lo(q0);
        acc[1] = acc[1] * scale + p * b2f_hi(q0);
        acc[2] = acc[2] * scale + p * b2f_lo(q1);
        acc[3] = acc[3] * scale + p * b2f_hi(q1);
        acc[4] = acc[4] * scale + p * b2f_lo(q2);
        acc[5] = acc[5] * scale + p * b2f_hi(q2);
        acc[6] = acc[6] * scale + p * b2f_lo(q3);
        acc[7] = acc[7] * scale + p * b2f_hi(q3);
        m = mn;
    }
    float inv = 1.f / (ssum + 1e-16f);
    int cbase = 8 * l;
    float v[8];
#pragma unroll
    for (int c = 0; c < 8; c++) {
        float t = acc[c] * inv + bias[cbase + c];
        if (elu) t = t > 0.f ? t : expm1f(t);
        v[c] = t;
    }
    u32* op = (u32*)(outb + (size_t)n * 512 + cbase);
    op[0] = pack2(f2b(v[0]), f2b(v[1]));
    op[1] = pack2(f2b(v[2]), f2b(v[3]));
    op[2] = pack2(f2b(v[4]), f2b(v[5]));
    op[3] = pack2(f2b(v[6]), f2b(v[7]));
}

// MFMA GEMM: C bf16[M,N] = A bf16[M,K] @ Bt bf16[N,K]^T (+bias fp32, opt relu).
// 128x128 tile, 4 waves 2x2, register-staged LDS, K multiple of 32.
__device__ void gemm_dev(const u16* __restrict__ A, const u16* __restrict__ Bt,
                         u16* __restrict__ C, const float* __restrict__ bias,
                         int M, int N, int K, int act, u16* As, u16* Bs) {
    const int t = threadIdx.x;
    const int l = t & 63, w = t >> 6;
    const int m0 = blockIdx.x * 128, n0 = blockIdx.y * 128;
    const int sr = t >> 2;             // 0..63
    const int sc = (t & 3) * 8;        // 16B chunks
    const int wm = (w >> 1) * 64, wn = (w & 1) * 64;

    const int rA0 = min(m0 + sr, M - 1);
    const int rA1 = min(m0 + sr + 64, M - 1);
    const int rB0 = min(n0 + sr, N - 1);
    const int rB1 = min(n0 + sr + 64, N - 1);

    f32x4 acc[4][4];
    f32x4 z4 = {0.f, 0.f, 0.f, 0.f};
#pragma unroll
    for (int i = 0; i < 4; i++)
#pragma unroll
        for (int j = 0; j < 4; j++) acc[i][j] = z4;

    for (int k0 = 0; k0 < K; k0 += 32) {
        short8 a0 = *(const short8*)(A + (size_t)rA0 * K + k0 + sc);
        short8 a1 = *(const short8*)(A + (size_t)rA1 * K + k0 + sc);
        short8 b0 = *(const short8*)(Bt + (size_t)rB0 * K + k0 + sc);
        short8 b1 = *(const short8*)(Bt + (size_t)rB1 * K + k0 + sc);
        __syncthreads();   // prior LDS reads done
        *(short8*)(As + sr * 32 + sc) = a0;
        *(short8*)(As + (sr + 64) * 32 + sc) = a1;
        *(short8*)(Bs + sr * 32 + sc) = b0;
        *(short8*)(Bs + (sr + 64) * 32 + sc) = b1;
        __syncthreads();

        bf16x8 af[4], bfr[4];
#pragma unroll
        for (int i = 0; i < 4; i++) {
            af[i]  = *(const bf16x8*)(As + (wm + i * 16 + (l & 15)) * 32 + (l >> 4) * 8);
            bfr[i] = *(const bf16x8*)(Bs + (wn + i * 16 + (l & 15)) * 32 + (l >> 4) * 8);
        }
#pragma unroll
        for (int i = 0; i < 4; i++)
#pragma unroll
            for (int j = 0; j < 4; j++)
                acc[i][j] = __builtin_amdgcn_mfma_f32_16x16x32_bf16(af[i], bfr[j], acc[i][j], 0, 0, 0);
    }

#pragma unroll
    for (int i = 0; i < 4; i++) {
        int rbase = m0 + wm + i * 16 + (l >> 4) * 4;
#pragma unroll
        for (int j = 0; j < 4; j++) {
            int c = n0 + wn + j * 16 + (l & 15);
            float bv = bias ? bias[c] : 0.f;
#pragma unroll
            for (int r = 0; r < 4; r++) {
                int row = rbase + r;
                if (row < M) {
                    float v = acc[i][j][r] + bv;
                    if (act) v = v > 0.f ? v : 0.f;
                    C[(size_t)row * N + c] = f2b(v);
                }
            }
        }
    }
}

__global__ __launch_bounds__(256) void BaselineGAT_41764261987077_kernel(
    int phase, int aux,
    const float* x, const int* ei,
    const float* W1, const float* as1, const float* ad1, const float* b1,
    const float* W2, const float* as2, const float* ad2, const float* b2,
    const float* Wc1, const float* bc1, const float* Wc2, const float* bc2,
    float* out,
    u16* hAb, u16* hbB, float* asr, float* ads,
    u16* xb, u16* w1t, u16* w2t, u16* wc1t,
    int* flag, int* cnt, int* tmp, int* bsum, int* boff,
    int* rowptr, int* cursor, int* col,
    const u16* gA, const u16* gB, u16* gC, const float* gBias,
    int gM, int gN, int gK, int gAct,
    int NODES, int E, int nblk)
{
    __shared__ float smf[1312];
    __shared__ int smi[257];
    __shared__ u16 As[128 * 32];
    __shared__ u16 Bs[128 * 32];
    const int t = threadIdx.x;
    const int gid = blockIdx.x * 256 + t;
    const int EN = E + NODES;

    switch (phase) {
    case 100: {   // tracer / ws-sentinel paint
        float v = (aux == 0) ? 0.25f : 1000.0f;
        if (gid < NODES * 10) out[gid] = v;
    } break;
    case 0: {     // edge dtype detect (int64 -> odd int32 slots all zero)
        if (t == 0) smi[256] = 0;
        __syncthreads();
        for (int j = t; j < 1024; j += 256)
            if (ei[2 * j + 1] != 0) atomicAdd(&smi[256], 1);
        __syncthreads();
        if (t == 0) flag[0] = (smi[256] < 16) ? 2 : 1;
    } break;
    case 1: { if (gid < NODES) cnt[gid] = 0; } break;
    case 2: {     // histogram of dst (+self loops)
        if (gid >= EN) return;
        int step = flag[0];
        int d;
        if (gid < E) {
            d = ei[(size_t)(E + gid) * step];
            if ((unsigned)d >= (unsigned)NODES) d = 0;
        } else d = gid - E;
        atomicAdd(&cnt[d], 1);
    } break;
    case 3: {     // block-local inclusive scan
        smi[t] = (gid < NODES) ? cnt[gid] : 0;
        __syncthreads();
        for (int o = 1; o < 256; o <<= 1) {
            int add = (t >= o) ? smi[t - o] : 0;
            __syncthreads();
            smi[t] += add;
            __syncthreads();
        }
        if (gid < NODES) tmp[gid] = smi[t];
        if (t == 255) bsum[blockIdx.x] = smi[255];
    } break;
    case 4: {
        if (blockIdx.x == 0 && t == 0) {
            int ex = 0;
            for (int b = 0; b < nblk; b++) { boff[b] = ex; ex += bsum[b]; }
        }
    } break;
    case 5: {
        if (gid >= NODES) return;
        int incl = tmp[gid] + boff[blockIdx.x];
        rowptr[gid + 1] = incl;
        cursor[gid] = incl - cnt[gid];
        if (gid == 0) rowptr[0] = 0;
    } break;
    case 6: {
        if (gid >= EN) return;
        int step = flag[0];
        int d, s;
        if (gid < E) {
            s = ei[(size_t)gid * step];
            d = ei[(size_t)(E + gid) * step];
            if ((unsigned)s >= (unsigned)NODES) s = 0;
            if ((unsigned)d >= (unsigned)NODES) d = 0;
        } else { d = gid - E; s = d; }
        int pos = atomicAdd(&cursor[d], 1);
        col[pos] = s;
    } break;
    case 20: {    // x fp32 [N,336] -> xb bf16 [N,352] zero-padded
        if (gid >= NODES * 352) return;
        int n = gid / 352, k = gid - n * 352;
        xb[gid] = (k < 336) ? f2b(x[(size_t)n * 336 + k]) : (u16)0;
    } break;
    case 21: {    // W1 [336,512] -> w1t bf16 [512,352] (transpose + pad)
        if (gid >= 512 * 352) return;
        int n = gid / 352, k = gid - n * 352;
        w1t[gid] = (k < 336) ? f2b(W1[(size_t)k * 512 + n]) : (u16)0;
    } break;
    case 22: {    // W2 [512,512] -> w2t bf16 [512,512] (transpose)
        if (gid >= 512 * 512) return;
        int n = gid >> 9, k = gid & 511;
        w2t[gid] = f2b(W2[(size_t)k * 512 + n]);
    } break;
    case 23: {    // Wc1 [512,128] -> wc1t bf16 [128,512] (transpose)
        if (gid >= 128 * 512) return;
        int n = gid >> 9, k = gid & 511;
        wc1t[gid] = f2b(Wc1[(size_t)k * 128 + n]);
    } break;
    case 30: gemm_dev(gA, gB, gC, gBias, gM, gN, gK, gAct, As, Bs); break;
    case 8:  alpha_dev(hAb, as1, ad1, asr, ads, smf, smf + 512); break;
    case 11: alpha_dev(hAb, as2, ad2, asr, ads, smf, smf + 512); break;
    case 31: agg_dev(rowptr, col, asr, ads, hAb, gBias, hbB, aux, NODES); break;
    case 14: {    // logits = z(=gC bf16)[N,128] @ Wc2[128,10] + bc2
        for (int i = t; i < 1280; i += 256) smf[i] = Wc2[i];
        if (t < 10) smf[1280 + t] = bc2[t];
        __syncthreads();
        int n = gid;
        if (n >= NODES) return;
        float acc[10];
        for (int c = 0; c < 10; c++) acc[c] = smf[1280 + c];
        const u16* zp = gA + (size_t)n * 128;
        for (int k = 0; k < 128; k++) {
            float f = b2f(zp[k]);
            const float* wr = &smf[k * 10];
            for (int c = 0; c < 10; c++) acc[c] += f * wr[c];
        }
        float* op = out + (size_t)n * 10;
        for (int c = 0; c < 10; c++) op[c] = acc[c];
    } break;
    }
}

extern "C" void kernel_launch(void* const* d_in, const int* in_sizes, int n_in,
                              void* d_out, int out_size, void* d_ws, size_t ws_size,
                              hipStream_t stream) {
    const float* x   = (const float*)d_in[0];
    const int*   ei  = (const int*)d_in[1];
    const float* W1  = (const float*)d_in[2];
    const float* as1 = (const float*)d_in[3];
    const float* ad1 = (const float*)d_in[4];
    const float* b1  = (const float*)d_in[5];
    const float* W2  = (const float*)d_in[6];
    const float* as2 = (const float*)d_in[7];
    const float* ad2 = (const float*)d_in[8];
    const float* b2  = (const float*)d_in[9];
    const float* Wc1 = (const float*)d_in[10];
    const float* bc1 = (const float*)d_in[11];
    const float* Wc2 = (const float*)d_in[12];
    const float* bc2 = (const float*)d_in[13];

    const int NODES = in_sizes[0] / 336;   // 50000
    const int E     = in_sizes[1] / 2;     // 500000

    char* ws = (char*)d_ws;
    size_t off = 0;
    auto alloc = [&](size_t b) -> char* {
        char* p = ws + off; off = (off + b + 255) & ~(size_t)255; return p;
    };
    u16*   xb   = (u16*)alloc((size_t)NODES * 352 * 2);   // reused as z later
    u16*   hAb  = (u16*)alloc((size_t)NODES * 512 * 2);   // GEMM out (bf16)
    u16*   hbB  = (u16*)alloc((size_t)NODES * 512 * 2);   // agg out (bf16)
    float* asr  = (float*)alloc((size_t)NODES * 4 * 4);
    float* ads  = (float*)alloc((size_t)NODES * 4 * 4);
    u16*   w1t  = (u16*)alloc((size_t)512 * 352 * 2);
    u16*   w2t  = (u16*)alloc((size_t)512 * 512 * 2);
    u16*   wc1t = (u16*)alloc((size_t)128 * 512 * 2);
    int* flag   = (int*)alloc(256);
    int* cnt    = (int*)alloc((size_t)NODES * 4);
    int* tmp    = (int*)alloc((size_t)NODES * 4);
    int* bsum   = (int*)alloc(4096);
    int* boff   = (int*)alloc(4096);
    int* rowptr = (int*)alloc((size_t)(NODES + 1) * 4);
    int* cursor = (int*)alloc((size_t)NODES * 4);
    int* col    = (int*)alloc((size_t)(E + NODES) * 4);
    u16* z      = xb;   // xb dead after GEMM1; z bf16 needs 12.8 MB <= 35.2 MB

    const int nblk = (NODES + 255) / 256;
    const int eblk = (E + NODES + 255) / 256;
    const int oblk = (out_size + 255) / 256;
    const int mt   = (NODES + 127) / 128;
    const int ablk = (NODES + 3) / 4;

    auto L = [&](int phase, int aux, dim3 grid,
                 const u16* gA = nullptr, const u16* gB = nullptr,
                 u16* gC = nullptr, const float* gBias = nullptr,
                 int gM = 0, int gN = 0, int gK = 0, int gAct = 0) {
        BaselineGAT_41764261987077_kernel<<<grid, 256, 0, stream>>>(
            phase, aux, x, ei, W1, as1, ad1, b1, W2, as2, ad2, b2,
            Wc1, bc1, Wc2, bc2, (float*)d_out,
            hAb, hbB, asr, ads, xb, w1t, w2t, wc1t,
            flag, cnt, tmp, bsum, boff, rowptr, cursor, col,
            gA, gB, gC, gBias, gM, gN, gK, gAct,
            NODES, E, nblk);
    };

    L(100, 0, oblk);                                    // tracer paint
    if (n_in < 14 || off > ws_size) { L(100, 1, oblk); return; }

    // CSR build
    L(0, 0, 1); L(1, 0, nblk); L(2, 0, eblk); L(3, 0, nblk);
    L(4, 0, 1); L(5, 0, nblk); L(6, 0, eblk);

    // bf16 conversions
    L(20, 0, (NODES * 352 + 255) / 256);
    L(21, 0, (512 * 352 + 255) / 256);
    L(22, 0, (512 * 512 + 255) / 256);
    L(23, 0, (128 * 512 + 255) / 256);

    // layer 1: h1 = xb @ w1t^T (bf16 out), alpha, agg(elu) -> hbB bf16
    L(30, 0, dim3(mt, 4), xb, w1t, hAb, nullptr, NODES, 512, 352, 0);
    L(8, 0, NODES);
    L(31, 1, ablk, nullptr, nullptr, nullptr, b1);

    // layer 2: h2 = hbB @ w2t^T, alpha, agg -> hbB' ... (reuse hAb/hbB ping-pong)
    L(30, 0, dim3(mt, 4), hbB, w2t, hAb, nullptr, NODES, 512, 512, 0);
    L(11, 0, NODES);
    L(31, 0, ablk, nullptr, nullptr, nullptr, b2);

    // classifier: z = relu(hbB @ wc1t^T + bc1) bf16, logits = z @ Wc2 + bc2
    L(30, 0, dim3(mt, 1), hbB, wc1t, z, bc1, NODES, 128, 512, 1);
    L(14, 0, nblk, z);
}

// Round 11
// 1148.304 us; speedup vs baseline: 3.3556x; 1.2625x over previous
//
#include <hip/hip_runtime.h>
#include <math.h>

typedef unsigned short u16;
typedef unsigned int u32;
typedef short short8 __attribute__((ext_vector_type(8)));
typedef __bf16 bf16x8 __attribute__((ext_vector_type(8)));
typedef float f32x4 __attribute__((ext_vector_type(4)));

__device__ __forceinline__ float b2f(u16 u) {
    union { u32 i; float f; } v; v.i = ((u32)u) << 16; return v.f;
}
__device__ __forceinline__ float b2f_lo(u32 q) {
    union { u32 i; float f; } v; v.i = q << 16; return v.f;
}
__device__ __forceinline__ float b2f_hi(u32 q) {
    union { u32 i; float f; } v; v.i = q & 0xffff0000u; return v.f;
}
__device__ __forceinline__ u16 f2b(float f) {
    union { float f; u32 i; } v; v.f = f;
    u32 i = v.i;
    u32 r = (i + 0x7fffu + ((i >> 16) & 1u)) >> 16;   // RNE fp32 -> bf16
    return (u16)r;
}
__device__ __forceinline__ u32 pack2(u16 a, u16 b) { return (u32)a | ((u32)b << 16); }

// ---------- device helpers (all phases live in the ONE named kernel) ----------

// segment softmax + aggregate. Wave-per-node (4 nodes/block); lane l owns
// channels 8l..8l+7 (head = l>>4). Two-pass softmax; pass2 2-way unrolled.
__device__ void agg_dev(const int* __restrict__ rowptr, const int* __restrict__ col,
                        const float* __restrict__ asrc, const float* __restrict__ adst,
                        const u16* __restrict__ hb, const float* __restrict__ bias,
                        u16* __restrict__ outb, int elu, int NODES) {
    int w = threadIdx.x >> 6, l = threadIdx.x & 63;
    int n = blockIdx.x * 4 + w;
    if (n >= NODES) return;
    int hd = l >> 4;
    int beg = rowptr[n], end = rowptr[n + 1];
    float ad = adst[n * 4 + hd];

    // pass 1: segment max
    float m = -1e30f;
    for (int j = beg; j < end; ++j) {
        float e = asrc[col[j] * 4 + hd] + ad;
        e = e > 0.f ? e : 0.2f * e;                    // leaky_relu(0.2)
        m = fmaxf(m, e);
    }

    // pass 2: accumulate exp(e-m)*h, 2-way unrolled independent accumulators
    float acc0[8], acc1[8];
#pragma unroll
    for (int c = 0; c < 8; c++) { acc0[c] = 0.f; acc1[c] = 0.f; }
    float ss0 = 0.f, ss1 = 0.f;
    int j = beg;
    for (; j + 1 < end; j += 2) {
        int s0 = col[j], s1 = col[j + 1];
        const u32* hp0 = (const u32*)(hb + (size_t)s0 * 512 + 8 * l);
        const u32* hp1 = (const u32*)(hb + (size_t)s1 * 512 + 8 * l);
        u32 q00 = hp0[0], q01 = hp0[1], q02 = hp0[2], q03 = hp0[3];
        u32 q10 = hp1[0], q11 = hp1[1], q12 = hp1[2], q13 = hp1[3];
        float e0 = asrc[s0 * 4 + hd] + ad; e0 = e0 > 0.f ? e0 : 0.2f * e0;
        float e1 = asrc[s1 * 4 + hd] + ad; e1 = e1 > 0.f ? e1 : 0.2f * e1;
        float p0 = __expf(e0 - m), p1 = __expf(e1 - m);
        ss0 += p0; ss1 += p1;
        acc0[0] += p0 * b2f_lo(q00); acc0[1] += p0 * b2f_hi(q00);
        acc0[2] += p0 * b2f_lo(q01); acc0[3] += p0 * b2f_hi(q01);
        acc0[4] += p0 * b2f_lo(q02); acc0[5] += p0 * b2f_hi(q02);
        acc0[6] += p0 * b2f_lo(q03); acc0[7] += p0 * b2f_hi(q03);
        acc1[0] += p1 * b2f_lo(q10); acc1[1] += p1 * b2f_hi(q10);
        acc1[2] += p1 * b2f_lo(q11); acc1[3] += p1 * b2f_hi(q11);
        acc1[4] += p1 * b2f_lo(q12); acc1[5] += p1 * b2f_hi(q12);
        acc1[6] += p1 * b2f_lo(q13); acc1[7] += p1 * b2f_hi(q13);
    }
    if (j < end) {
        int s0 = col[j];
        const u32* hp0 = (const u32*)(hb + (size_t)s0 * 512 + 8 * l);
        u32 q00 = hp0[0], q01 = hp0[1], q02 = hp0[2], q03 = hp0[3];
        float e0 = asrc[s0 * 4 + hd] + ad; e0 = e0 > 0.f ? e0 : 0.2f * e0;
        float p0 = __expf(e0 - m);
        ss0 += p0;
        acc0[0] += p0 * b2f_lo(q00); acc0[1] += p0 * b2f_hi(q00);
        acc0[2] += p0 * b2f_lo(q01); acc0[3] += p0 * b2f_hi(q01);
        acc0[4] += p0 * b2f_lo(q02); acc0[5] += p0 * b2f_hi(q02);
        acc0[6] += p0 * b2f_lo(q03); acc0[7] += p0 * b2f_hi(q03);
    }
    float inv = 1.f / (ss0 + ss1 + 1e-16f);
    int cbase = 8 * l;
    float v[8];
#pragma unroll
    for (int c = 0; c < 8; c++) {
        float t = (acc0[c] + acc1[c]) * inv + bias[cbase + c];
        if (elu) t = t > 0.f ? t : expm1f(t);
        v[c] = t;
    }
    u32* op = (u32*)(outb + (size_t)n * 512 + cbase);
    op[0] = pack2(f2b(v[0]), f2b(v[1]));
    op[1] = pack2(f2b(v[2]), f2b(v[3]));
    op[2] = pack2(f2b(v[4]), f2b(v[5]));
    op[3] = pack2(f2b(v[6]), f2b(v[7]));
}

// MFMA GEMM: C bf16[M,N] = A bf16[M,K] @ Bt bf16[N,K]^T (+bias fp32, opt relu).
// 128x128 tile, 4 waves 2x2, register-staged LDS, K multiple of 32.
// Fused alpha epilogue (aS != nullptr): per-row dot over this block's 128
// columns (= one head). Each wave reduces its OWN 64-column half via shfl;
// the two column-half waves are then combined through LDS `red` (this was
// the round-10 race: both halves plain-stored to the same address).
__device__ void gemm_dev(const u16* __restrict__ A, const u16* __restrict__ Bt,
                         u16* __restrict__ C, const float* __restrict__ bias,
                         const float* __restrict__ aS, const float* __restrict__ aD,
                         float* __restrict__ asr, float* __restrict__ ads,
                         int M, int N, int K, int act, u16* As, u16* Bs,
                         float (*red)[128][2]) {
    const int t = threadIdx.x;
    const int l = t & 63, w = t >> 6;
    const int m0 = blockIdx.x * 128, n0 = blockIdx.y * 128;
    const int sr = t >> 2;             // 0..63
    const int sc = (t & 3) * 8;        // 16B chunks
    const int wm = (w >> 1) * 64, wn = (w & 1) * 64;

    const int rA0 = min(m0 + sr, M - 1);
    const int rA1 = min(m0 + sr + 64, M - 1);
    const int rB0 = min(n0 + sr, N - 1);
    const int rB1 = min(n0 + sr + 64, N - 1);

    f32x4 acc[4][4];
    f32x4 z4 = {0.f, 0.f, 0.f, 0.f};
#pragma unroll
    for (int i = 0; i < 4; i++)
#pragma unroll
        for (int j = 0; j < 4; j++) acc[i][j] = z4;

    for (int k0 = 0; k0 < K; k0 += 32) {
        short8 a0 = *(const short8*)(A + (size_t)rA0 * K + k0 + sc);
        short8 a1 = *(const short8*)(A + (size_t)rA1 * K + k0 + sc);
        short8 b0 = *(const short8*)(Bt + (size_t)rB0 * K + k0 + sc);
        short8 b1 = *(const short8*)(Bt + (size_t)rB1 * K + k0 + sc);
        __syncthreads();   // prior LDS reads done
        *(short8*)(As + sr * 32 + sc) = a0;
        *(short8*)(As + (sr + 64) * 32 + sc) = a1;
        *(short8*)(Bs + sr * 32 + sc) = b0;
        *(short8*)(Bs + (sr + 64) * 32 + sc) = b1;
        __syncthreads();

        bf16x8 af[4], bfr[4];
#pragma unroll
        for (int i = 0; i < 4; i++) {
            af[i]  = *(const bf16x8*)(As + (wm + i * 16 + (l & 15)) * 32 + (l >> 4) * 8);
            bfr[i] = *(const bf16x8*)(Bs + (wn + i * 16 + (l & 15)) * 32 + (l >> 4) * 8);
        }
#pragma unroll
        for (int i = 0; i < 4; i++)
#pragma unroll
            for (int j = 0; j < 4; j++)
                acc[i][j] = __builtin_amdgcn_mfma_f32_16x16x32_bf16(af[i], bfr[j], acc[i][j], 0, 0, 0);
    }

#pragma unroll
    for (int i = 0; i < 4; i++) {
        int rbase = m0 + wm + i * 16 + (l >> 4) * 4;
#pragma unroll
        for (int j = 0; j < 4; j++) {
            int c = n0 + wn + j * 16 + (l & 15);
            float bv = bias ? bias[c] : 0.f;
#pragma unroll
            for (int r = 0; r < 4; r++) {
                int row = rbase + r;
                if (row < M) {
                    float v = acc[i][j][r] + bv;
                    if (act) v = v > 0.f ? v : 0.f;
                    C[(size_t)row * N + c] = f2b(v);
                }
            }
        }
    }

    if (aS) {   // fused alpha epilogue; head hd = n0/128
        const int hd = n0 >> 7;
        float aSv[4], aDv[4];
#pragma unroll
        for (int j = 0; j < 4; j++) {
            int c = n0 + wn + j * 16 + (l & 15);
            aSv[j] = aS[c];
            aDv[j] = aD[c];
        }
#pragma unroll
        for (int i = 0; i < 4; i++) {
#pragma unroll
            for (int r = 0; r < 4; r++) {
                float vs = 0.f, vd = 0.f;
#pragma unroll
                for (int j = 0; j < 4; j++) {
                    float hv = acc[i][j][r];
                    vs += hv * aSv[j];
                    vd += hv * aDv[j];
                }
#pragma unroll
                for (int o = 1; o < 16; o <<= 1) {
                    vs += __shfl_xor(vs, o);
                    vd += __shfl_xor(vd, o);
                }
                if ((l & 15) == 0) {
                    int rl = wm + i * 16 + (l >> 4) * 4 + r;   // 0..127 local row
                    red[w & 1][rl][0] = vs;                    // column-half partial
                    red[w & 1][rl][1] = vd;
                }
            }
        }
        __syncthreads();
        if (t < 128) {
            int row = m0 + t;
            if (row < M) {
                asr[row * 4 + hd] = red[0][t][0] + red[1][t][0];
                ads[row * 4 + hd] = red[0][t][1] + red[1][t][1];
            }
        }
    }
}

__global__ __launch_bounds__(256) void BaselineGAT_41764261987077_kernel(
    int phase, int aux,
    const float* x, const int* ei,
    const float* W1, const float* as1, const float* ad1, const float* b1,
    const float* W2, const float* as2, const float* ad2, const float* b2,
    const float* Wc1, const float* bc1, const float* Wc2, const float* bc2,
    float* out,
    u16* hAb, u16* hbB, float* asr, float* ads,
    u16* xb, u16* w1t, u16* w2t, u16* wc1t,
    int* flag, int* cnt, int* tmp, int* bsum, int* boff,
    int* rowptr, int* cursor, int* col,
    const u16* gA, const u16* gB, u16* gC, const float* gBias,
    const float* gAs, const float* gAd,
    int gM, int gN, int gK, int gAct,
    int NODES, int E, int nblk)
{
    __shared__ float smf[1312];
    __shared__ int smi[257];
    __shared__ u16 As[128 * 32];
    __shared__ u16 Bs[128 * 32];
    __shared__ float red[2][128][2];
    const int t = threadIdx.x;
    const int gid = blockIdx.x * 256 + t;
    const int EN = E + NODES;

    switch (phase) {
    case 100: {   // tracer / ws-sentinel paint
        float v = (aux == 0) ? 0.25f : 1000.0f;
        if (gid < NODES * 10) out[gid] = v;
    } break;
    case 0: {     // block 0: edge dtype detect; other blocks: zero cnt
        if (blockIdx.x == 0) {
            if (t == 0) smi[256] = 0;
            __syncthreads();
            for (int j = t; j < 1024; j += 256)
                if (ei[2 * j + 1] != 0) atomicAdd(&smi[256], 1);
            __syncthreads();
            if (t == 0) flag[0] = (smi[256] < 16) ? 2 : 1;
        } else {
            int i = (blockIdx.x - 1) * 256 + t;
            if (i < NODES) cnt[i] = 0;
        }
    } break;
    case 2: {     // histogram of dst (+self loops)
        if (gid >= EN) return;
        int step = flag[0];
        int d;
        if (gid < E) {
            d = ei[(size_t)(E + gid) * step];
            if ((unsigned)d >= (unsigned)NODES) d = 0;
        } else d = gid - E;
        atomicAdd(&cnt[d], 1);
    } break;
    case 3: {     // block-local inclusive scan
        smi[t] = (gid < NODES) ? cnt[gid] : 0;
        __syncthreads();
        for (int o = 1; o < 256; o <<= 1) {
            int add = (t >= o) ? smi[t - o] : 0;
            __syncthreads();
            smi[t] += add;
            __syncthreads();
        }
        if (gid < NODES) tmp[gid] = smi[t];
        if (t == 255) bsum[blockIdx.x] = smi[255];
    } break;
    case 4: {
        if (blockIdx.x == 0 && t == 0) {
            int ex = 0;
            for (int b = 0; b < nblk; b++) { boff[b] = ex; ex += bsum[b]; }
        }
    } break;
    case 5: {
        if (gid >= NODES) return;
        int incl = tmp[gid] + boff[blockIdx.x];
        rowptr[gid + 1] = incl;
        cursor[gid] = incl - cnt[gid];
        if (gid == 0) rowptr[0] = 0;
    } break;
    case 6: {
        if (gid >= EN) return;
        int step = flag[0];
        int d, s;
        if (gid < E) {
            s = ei[(size_t)gid * step];
            d = ei[(size_t)(E + gid) * step];
            if ((unsigned)s >= (unsigned)NODES) s = 0;
            if ((unsigned)d >= (unsigned)NODES) d = 0;
        } else { d = gid - E; s = d; }
        int pos = atomicAdd(&cursor[d], 1);
        col[pos] = s;
    } break;
    case 20: {    // all bf16 conversions in one dispatch
        int i = gid;
        int R0 = NODES * 352;
        if (i < R0) {                 // x [N,336] -> xb [N,352] padded
            int n = i / 352, k = i - n * 352;
            xb[i] = (k < 336) ? f2b(x[(size_t)n * 336 + k]) : (u16)0;
            return;
        }
        i -= R0;
        if (i < 512 * 352) {          // W1 [336,512] -> w1t [512,352] T+pad
            int n = i / 352, k = i - n * 352;
            w1t[i] = (k < 336) ? f2b(W1[(size_t)k * 512 + n]) : (u16)0;
            return;
        }
        i -= 512 * 352;
        if (i < 512 * 512) {          // W2 [512,512] -> w2t [512,512] T
            int n = i >> 9, k = i & 511;
            w2t[i] = f2b(W2[(size_t)k * 512 + n]);
            return;
        }
        i -= 512 * 512;
        if (i < 128 * 512) {          // Wc1 [512,128] -> wc1t [128,512] T
            int n = i >> 9, k = i & 511;
            wc1t[i] = f2b(Wc1[(size_t)k * 128 + n]);
        }
    } break;
    case 30: gemm_dev(gA, gB, gC, gBias, gAs, gAd, asr, ads,
                      gM, gN, gK, gAct, As, Bs, red); break;
    case 31: agg_dev(rowptr, col, asr, ads, hAb, gBias, hbB, aux, NODES); break;
    case 14: {    // logits = z(=gA bf16)[N,128] @ Wc2[128,10] + bc2
        for (int i = t; i < 1280; i += 256) smf[i] = Wc2[i];
        if (t < 10) smf[1280 + t] = bc2[t];
        __syncthreads();
        int n = gid;
        if (n >= NODES) return;
        float acc[10];
        for (int c = 0; c < 10; c++) acc[c] = smf[1280 + c];
        const u16* zp = gA + (size_t)n * 128;
        for (int k = 0; k < 128; k++) {
            float f = b2f(zp[k]);
            const float* wr = &smf[k * 10];
            for (int c = 0; c < 10; c++) acc[c] += f * wr[c];
        }
        float* op = out + (size_t)n * 10;
        for (int c = 0; c < 10; c++) op[c] = acc[c];
    } break;
    }
}

extern "C" void kernel_launch(void* const* d_in, const int* in_sizes, int n_in,
                              void* d_out, int out_size, void* d_ws, size_t ws_size,
                              hipStream_t stream) {
    const float* x   = (const float*)d_in[0];
    const int*   ei  = (const int*)d_in[1];
    const float* W1  = (const float*)d_in[2];
    const float* as1 = (const float*)d_in[3];
    const float* ad1 = (const float*)d_in[4];
    const float* b1  = (const float*)d_in[5];
    const float* W2  = (const float*)d_in[6];
    const float* as2 = (const float*)d_in[7];
    const float* ad2 = (const float*)d_in[8];
    const float* b2  = (const float*)d_in[9];
    const float* Wc1 = (const float*)d_in[10];
    const float* bc1 = (const float*)d_in[11];
    const float* Wc2 = (const float*)d_in[12];
    const float* bc2 = (const float*)d_in[13];

    const int NODES = in_sizes[0] / 336;   // 50000
    const int E     = in_sizes[1] / 2;     // 500000

    char* ws = (char*)d_ws;
    size_t off = 0;
    auto alloc = [&](size_t b) -> char* {
        char* p = ws + off; off = (off + b + 255) & ~(size_t)255; return p;
    };
    u16*   xb   = (u16*)alloc((size_t)NODES * 352 * 2);   // reused as z later
    u16*   hAb  = (u16*)alloc((size_t)NODES * 512 * 2);   // GEMM out (bf16)
    u16*   hbB  = (u16*)alloc((size_t)NODES * 512 * 2);   // agg out (bf16)
    float* asr  = (float*)alloc((size_t)NODES * 4 * 4);
    float* ads  = (float*)alloc((size_t)NODES * 4 * 4);
    u16*   w1t  = (u16*)alloc((size_t)512 * 352 * 2);
    u16*   w2t  = (u16*)alloc((size_t)512 * 512 * 2);
    u16*   wc1t = (u16*)alloc((size_t)128 * 512 * 2);
    int* flag   = (int*)alloc(256);
    int* cnt    = (int*)alloc((size_t)NODES * 4);
    int* tmp    = (int*)alloc((size_t)NODES * 4);
    int* bsum   = (int*)alloc(4096);
    int* boff   = (int*)alloc(4096);
    int* rowptr = (int*)alloc((size_t)(NODES + 1) * 4);
    int* cursor = (int*)alloc((size_t)NODES * 4);
    int* col    = (int*)alloc((size_t)(E + NODES) * 4);
    u16* z      = xb;   // xb dead after GEMM1

    const int nblk = (NODES + 255) / 256;
    const int eblk = (E + NODES + 255) / 256;
    const int oblk = (out_size + 255) / 256;
    const int mt   = (NODES + 127) / 128;
    const int ablk = (NODES + 3) / 4;
    const int cvt_total = NODES * 352 + 512 * 352 + 512 * 512 + 128 * 512;

    auto L = [&](int phase, int aux, dim3 grid,
                 const u16* gA = nullptr, const u16* gB = nullptr,
                 u16* gC = nullptr, const float* gBias = nullptr,
                 const float* gAs = nullptr, const float* gAd = nullptr,
                 int gM = 0, int gN = 0, int gK = 0, int gAct = 0) {
        BaselineGAT_41764261987077_kernel<<<grid, 256, 0, stream>>>(
            phase, aux, x, ei, W1, as1, ad1, b1, W2, as2, ad2, b2,
            Wc1, bc1, Wc2, bc2, (float*)d_out,
            hAb, hbB, asr, ads, xb, w1t, w2t, wc1t,
            flag, cnt, tmp, bsum, boff, rowptr, cursor, col,
            gA, gB, gC, gBias, gAs, gAd, gM, gN, gK, gAct,
            NODES, E, nblk);
    };

    L(100, 0, oblk);                                    // tracer paint
    if (n_in < 14 || off > ws_size) { L(100, 1, oblk); return; }

    // CSR build (detect+zero merged)
    L(0, 0, nblk + 1);
    L(2, 0, eblk);
    L(3, 0, nblk);
    L(4, 0, 1);
    L(5, 0, nblk);
    L(6, 0, eblk);

    // bf16 conversions (single dispatch)
    L(20, 0, (cvt_total + 255) / 256);

    // layer 1: h1 = xb @ w1t^T (bf16) + fused alpha, agg(elu) -> hbB
    L(30, 0, dim3(mt, 4), xb, w1t, hAb, nullptr, as1, ad1, NODES, 512, 352, 0);
    L(31, 1, ablk, nullptr, nullptr, nullptr, b1);

    // layer 2
    L(30, 0, dim3(mt, 4), hbB, w2t, hAb, nullptr, as2, ad2, NODES, 512, 512, 0);
    L(31, 0, ablk, nullptr, nullptr, nullptr, b2);

    // classifier: z = relu(hbB @ wc1t^T + bc1) bf16, logits = z @ Wc2 + bc2
    L(30, 0, dim3(mt, 1), hbB, wc1t, z, bc1, nullptr, nullptr, NODES, 128, 512, 1);
    L(14, 0, nblk, z);
}

// Round 12
// 759.310 us; speedup vs baseline: 5.0746x; 1.5123x over previous
//
#include <hip/hip_runtime.h>
#include <math.h>

typedef unsigned short u16;
typedef unsigned int u32;
typedef short short8 __attribute__((ext_vector_type(8)));
typedef __bf16 bf16x8 __attribute__((ext_vector_type(8)));
typedef float f32x4 __attribute__((ext_vector_type(4)));

__device__ __forceinline__ float b2f(u16 u) {
    union { u32 i; float f; } v; v.i = ((u32)u) << 16; return v.f;
}
__device__ __forceinline__ float b2f_lo(u32 q) {
    union { u32 i; float f; } v; v.i = q << 16; return v.f;
}
__device__ __forceinline__ float b2f_hi(u32 q) {
    union { u32 i; float f; } v; v.i = q & 0xffff0000u; return v.f;
}
__device__ __forceinline__ u16 f2b(float f) {
    union { float f; u32 i; } v; v.f = f;
    u32 i = v.i;
    u32 r = (i + 0x7fffu + ((i >> 16) & 1u)) >> 16;   // RNE fp32 -> bf16
    return (u16)r;
}
__device__ __forceinline__ u32 pack2(u16 a, u16 b) { return (u32)a | ((u32)b << 16); }

// ---------- device helpers (all phases live in the ONE named kernel) ----------

// segment softmax + aggregate. PERSISTENT waves: each wave grid-strides over
// nodes; lane l owns channels 8l..8l+7 (head = l>>4). No max-subtraction
// (|e| <~ 15 -> exp() fp32-safe; softmax ratio identical). 4-way unrolled:
// four independent 16B gathers in flight per iteration.
__device__ void agg_dev(const int* __restrict__ rowptr, const int* __restrict__ col,
                        const float* __restrict__ asrc, const float* __restrict__ adst,
                        const u16* __restrict__ hb, const float* __restrict__ bias,
                        u16* __restrict__ outb, int elu, int NODES) {
    const int wid = (blockIdx.x * 256 + threadIdx.x) >> 6;
    const int nwaves = gridDim.x << 2;
    const int l = threadIdx.x & 63;
    const int hd = l >> 4;
    const int cbase = 8 * l;
    float bv[8];
#pragma unroll
    for (int c = 0; c < 8; c++) bv[c] = bias[cbase + c];

    for (int n = wid; n < NODES; n += nwaves) {
        int beg = rowptr[n], end = rowptr[n + 1];
        float ad = adst[n * 4 + hd];
        float acc0[8], acc1[8];
#pragma unroll
        for (int c = 0; c < 8; c++) { acc0[c] = 0.f; acc1[c] = 0.f; }
        float ss0 = 0.f, ss1 = 0.f;
        int j = beg;
        for (; j + 3 < end; j += 4) {
            int s0 = col[j], s1 = col[j + 1], s2 = col[j + 2], s3 = col[j + 3];
            const u32* hp0 = (const u32*)(hb + (size_t)s0 * 512 + cbase);
            const u32* hp1 = (const u32*)(hb + (size_t)s1 * 512 + cbase);
            const u32* hp2 = (const u32*)(hb + (size_t)s2 * 512 + cbase);
            const u32* hp3 = (const u32*)(hb + (size_t)s3 * 512 + cbase);
            u32 q00 = hp0[0], q01 = hp0[1], q02 = hp0[2], q03 = hp0[3];
            u32 q10 = hp1[0], q11 = hp1[1], q12 = hp1[2], q13 = hp1[3];
            u32 q20 = hp2[0], q21 = hp2[1], q22 = hp2[2], q23 = hp2[3];
            u32 q30 = hp3[0], q31 = hp3[1], q32 = hp3[2], q33 = hp3[3];
            float e0 = asrc[s0 * 4 + hd] + ad; e0 = e0 > 0.f ? e0 : 0.2f * e0;
            float e1 = asrc[s1 * 4 + hd] + ad; e1 = e1 > 0.f ? e1 : 0.2f * e1;
            float e2 = asrc[s2 * 4 + hd] + ad; e2 = e2 > 0.f ? e2 : 0.2f * e2;
            float e3 = asrc[s3 * 4 + hd] + ad; e3 = e3 > 0.f ? e3 : 0.2f * e3;
            float p0 = __expf(e0), p1 = __expf(e1), p2 = __expf(e2), p3 = __expf(e3);
            ss0 += p0 + p2; ss1 += p1 + p3;
            acc0[0] += p0 * b2f_lo(q00) + p2 * b2f_lo(q20);
            acc0[1] += p0 * b2f_hi(q00) + p2 * b2f_hi(q20);
            acc0[2] += p0 * b2f_lo(q01) + p2 * b2f_lo(q21);
            acc0[3] += p0 * b2f_hi(q01) + p2 * b2f_hi(q21);
            acc0[4] += p0 * b2f_lo(q02) + p2 * b2f_lo(q22);
            acc0[5] += p0 * b2f_hi(q02) + p2 * b2f_hi(q22);
            acc0[6] += p0 * b2f_lo(q03) + p2 * b2f_lo(q23);
            acc0[7] += p0 * b2f_hi(q03) + p2 * b2f_hi(q23);
            acc1[0] += p1 * b2f_lo(q10) + p3 * b2f_lo(q30);
            acc1[1] += p1 * b2f_hi(q10) + p3 * b2f_hi(q30);
            acc1[2] += p1 * b2f_lo(q11) + p3 * b2f_lo(q31);
            acc1[3] += p1 * b2f_hi(q11) + p3 * b2f_hi(q31);
            acc1[4] += p1 * b2f_lo(q12) + p3 * b2f_lo(q32);
            acc1[5] += p1 * b2f_hi(q12) + p3 * b2f_hi(q32);
            acc1[6] += p1 * b2f_lo(q13) + p3 * b2f_lo(q33);
            acc1[7] += p1 * b2f_hi(q13) + p3 * b2f_hi(q33);
        }
        for (; j < end; ++j) {
            int s0 = col[j];
            const u32* hp0 = (const u32*)(hb + (size_t)s0 * 512 + cbase);
            u32 q00 = hp0[0], q01 = hp0[1], q02 = hp0[2], q03 = hp0[3];
            float e0 = asrc[s0 * 4 + hd] + ad; e0 = e0 > 0.f ? e0 : 0.2f * e0;
            float p0 = __expf(e0);
            ss0 += p0;
            acc0[0] += p0 * b2f_lo(q00); acc0[1] += p0 * b2f_hi(q00);
            acc0[2] += p0 * b2f_lo(q01); acc0[3] += p0 * b2f_hi(q01);
            acc0[4] += p0 * b2f_lo(q02); acc0[5] += p0 * b2f_hi(q02);
            acc0[6] += p0 * b2f_lo(q03); acc0[7] += p0 * b2f_hi(q03);
        }
        float inv = 1.f / (ss0 + ss1 + 1e-16f);
        float v[8];
#pragma unroll
        for (int c = 0; c < 8; c++) {
            float tv = (acc0[c] + acc1[c]) * inv + bv[c];
            if (elu) tv = tv > 0.f ? tv : expm1f(tv);
            v[c] = tv;
        }
        u32* op = (u32*)(outb + (size_t)n * 512 + cbase);
        op[0] = pack2(f2b(v[0]), f2b(v[1]));
        op[1] = pack2(f2b(v[2]), f2b(v[3]));
        op[2] = pack2(f2b(v[4]), f2b(v[5]));
        op[3] = pack2(f2b(v[6]), f2b(v[7]));
    }
}

// MFMA GEMM: C bf16[M,N] = A bf16[M,K] @ Bt bf16[N,K]^T (+bias fp32, opt relu).
// 128x128 tile, 4 waves 2x2, register-staged LDS, K multiple of 32.
// Fused alpha epilogue (aS != nullptr): per-row dot over this block's 128
// columns (= one head); per-wave 16-lane shfl reduce, column-half combine
// through LDS `red` (round-10 race fix).
__device__ void gemm_dev(const u16* __restrict__ A, const u16* __restrict__ Bt,
                         u16* __restrict__ C, const float* __restrict__ bias,
                         const float* __restrict__ aS, const float* __restrict__ aD,
                         float* __restrict__ asr, float* __restrict__ ads,
                         int M, int N, int K, int act, u16* As, u16* Bs,
                         float (*red)[128][2]) {
    const int t = threadIdx.x;
    const int l = t & 63, w = t >> 6;
    const int m0 = blockIdx.x * 128, n0 = blockIdx.y * 128;
    const int sr = t >> 2;             // 0..63
    const int sc = (t & 3) * 8;        // 16B chunks
    const int wm = (w >> 1) * 64, wn = (w & 1) * 64;

    const int rA0 = min(m0 + sr, M - 1);
    const int rA1 = min(m0 + sr + 64, M - 1);
    const int rB0 = min(n0 + sr, N - 1);
    const int rB1 = min(n0 + sr + 64, N - 1);

    f32x4 acc[4][4];
    f32x4 z4 = {0.f, 0.f, 0.f, 0.f};
#pragma unroll
    for (int i = 0; i < 4; i++)
#pragma unroll
        for (int j = 0; j < 4; j++) acc[i][j] = z4;

    for (int k0 = 0; k0 < K; k0 += 32) {
        short8 a0 = *(const short8*)(A + (size_t)rA0 * K + k0 + sc);
        short8 a1 = *(const short8*)(A + (size_t)rA1 * K + k0 + sc);
        short8 b0 = *(const short8*)(Bt + (size_t)rB0 * K + k0 + sc);
        short8 b1 = *(const short8*)(Bt + (size_t)rB1 * K + k0 + sc);
        __syncthreads();   // prior LDS reads done
        *(short8*)(As + sr * 32 + sc) = a0;
        *(short8*)(As + (sr + 64) * 32 + sc) = a1;
        *(short8*)(Bs + sr * 32 + sc) = b0;
        *(short8*)(Bs + (sr + 64) * 32 + sc) = b1;
        __syncthreads();

        bf16x8 af[4], bfr[4];
#pragma unroll
        for (int i = 0; i < 4; i++) {
            af[i]  = *(const bf16x8*)(As + (wm + i * 16 + (l & 15)) * 32 + (l >> 4) * 8);
            bfr[i] = *(const bf16x8*)(Bs + (wn + i * 16 + (l & 15)) * 32 + (l >> 4) * 8);
        }
#pragma unroll
        for (int i = 0; i < 4; i++)
#pragma unroll
            for (int j = 0; j < 4; j++)
                acc[i][j] = __builtin_amdgcn_mfma_f32_16x16x32_bf16(af[i], bfr[j], acc[i][j], 0, 0, 0);
    }

#pragma unroll
    for (int i = 0; i < 4; i++) {
        int rbase = m0 + wm + i * 16 + (l >> 4) * 4;
#pragma unroll
        for (int j = 0; j < 4; j++) {
            int c = n0 + wn + j * 16 + (l & 15);
            float bv = bias ? bias[c] : 0.f;
#pragma unroll
            for (int r = 0; r < 4; r++) {
                int row = rbase + r;
                if (row < M) {
                    float v = acc[i][j][r] + bv;
                    if (act) v = v > 0.f ? v : 0.f;
                    C[(size_t)row * N + c] = f2b(v);
                }
            }
        }
    }

    if (aS) {   // fused alpha epilogue; head hd = n0/128
        const int hd = n0 >> 7;
        float aSv[4], aDv[4];
#pragma unroll
        for (int j = 0; j < 4; j++) {
            int c = n0 + wn + j * 16 + (l & 15);
            aSv[j] = aS[c];
            aDv[j] = aD[c];
        }
#pragma unroll
        for (int i = 0; i < 4; i++) {
#pragma unroll
            for (int r = 0; r < 4; r++) {
                float vs = 0.f, vd = 0.f;
#pragma unroll
                for (int j = 0; j < 4; j++) {
                    float hv = acc[i][j][r];
                    vs += hv * aSv[j];
                    vd += hv * aDv[j];
                }
#pragma unroll
                for (int o = 1; o < 16; o <<= 1) {
                    vs += __shfl_xor(vs, o);
                    vd += __shfl_xor(vd, o);
                }
                if ((l & 15) == 0) {
                    int rl = wm + i * 16 + (l >> 4) * 4 + r;   // 0..127 local row
                    red[w & 1][rl][0] = vs;                    // column-half partial
                    red[w & 1][rl][1] = vd;
                }
            }
        }
        __syncthreads();
        if (t < 128) {
            int row = m0 + t;
            if (row < M) {
                asr[row * 4 + hd] = red[0][t][0] + red[1][t][0];
                ads[row * 4 + hd] = red[0][t][1] + red[1][t][1];
            }
        }
    }
}

__global__ __launch_bounds__(256) void BaselineGAT_41764261987077_kernel(
    int phase, int aux,
    const float* x, const int* ei,
    const float* W1, const float* as1, const float* ad1, const float* b1,
    const float* W2, const float* as2, const float* ad2, const float* b2,
    const float* Wc1, const float* bc1, const float* Wc2, const float* bc2,
    float* out,
    u16* hAb, u16* hbB, float* asr, float* ads,
    u16* xb, u16* w1t, u16* w2t, u16* wc1t,
    int* flag, int* cnt, int* tmp, int* bsum, int* boff,
    int* rowptr, int* cursor, int* col,
    const u16* gA, const u16* gB, u16* gC, const float* gBias,
    const float* gAs, const float* gAd,
    int gM, int gN, int gK, int gAct,
    int NODES, int E, int nblk)
{
    // One aliased LDS arena (18.5 KB) instead of disjoint arrays (25 KB):
    // GEMM: As(8K)+Bs(8K)+red(2K); logits: smf(5.2K); scans: smi(1K).
    __shared__ f32x4 shm4[1156];   // 18496 B, 16B-aligned
    char* shm = (char*)shm4;
    u16* As = (u16*)shm;
    u16* Bs = (u16*)(shm + 8192);
    float (*red)[128][2] = (float (*)[128][2])(shm + 16384);
    float* smf = (float*)shm;
    int* smi = (int*)shm;

    const int t = threadIdx.x;
    const int gid = blockIdx.x * 256 + t;
    const int EN = E + NODES;

    switch (phase) {
    case 100: {   // tracer / ws-sentinel paint
        float v = (aux == 0) ? 0.25f : 1000.0f;
        if (gid < NODES * 10) out[gid] = v;
    } break;
    case 0: {     // block 0: edge dtype detect; other blocks: zero cnt
        if (blockIdx.x == 0) {
            if (t == 0) smi[256] = 0;
            __syncthreads();
            for (int j = t; j < 1024; j += 256)
                if (ei[2 * j + 1] != 0) atomicAdd(&smi[256], 1);
            __syncthreads();
            if (t == 0) flag[0] = (smi[256] < 16) ? 2 : 1;
        } else {
            int i = (blockIdx.x - 1) * 256 + t;
            if (i < NODES) cnt[i] = 0;
        }
    } break;
    case 2: {     // histogram of dst (+self loops)
        if (gid >= EN) return;
        int step = flag[0];
        int d;
        if (gid < E) {
            d = ei[(size_t)(E + gid) * step];
            if ((unsigned)d >= (unsigned)NODES) d = 0;
        } else d = gid - E;
        atomicAdd(&cnt[d], 1);
    } break;
    case 3: {     // block-local inclusive scan
        smi[t] = (gid < NODES) ? cnt[gid] : 0;
        __syncthreads();
        for (int o = 1; o < 256; o <<= 1) {
            int add = (t >= o) ? smi[t - o] : 0;
            __syncthreads();
            smi[t] += add;
            __syncthreads();
        }
        if (gid < NODES) tmp[gid] = smi[t];
        if (t == 255) bsum[blockIdx.x] = smi[255];
    } break;
    case 4: {
        if (blockIdx.x == 0 && t == 0) {
            int ex = 0;
            for (int b = 0; b < nblk; b++) { boff[b] = ex; ex += bsum[b]; }
        }
    } break;
    case 5: {
        if (gid >= NODES) return;
        int incl = tmp[gid] + boff[blockIdx.x];
        rowptr[gid + 1] = incl;
        cursor[gid] = incl - cnt[gid];
        if (gid == 0) rowptr[0] = 0;
    } break;
    case 6: {
        if (gid >= EN) return;
        int step = flag[0];
        int d, s;
        if (gid < E) {
            s = ei[(size_t)gid * step];
            d = ei[(size_t)(E + gid) * step];
            if ((unsigned)s >= (unsigned)NODES) s = 0;
            if ((unsigned)d >= (unsigned)NODES) d = 0;
        } else { d = gid - E; s = d; }
        int pos = atomicAdd(&cursor[d], 1);
        col[pos] = s;
    } break;
    case 20: {    // all bf16 conversions in one dispatch
        int i = gid;
        int R0 = NODES * 352;
        if (i < R0) {                 // x [N,336] -> xb [N,352] padded
            int n = i / 352, k = i - n * 352;
            xb[i] = (k < 336) ? f2b(x[(size_t)n * 336 + k]) : (u16)0;
            return;
        }
        i -= R0;
        if (i < 512 * 352) {          // W1 [336,512] -> w1t [512,352] T+pad
            int n = i / 352, k = i - n * 352;
            w1t[i] = (k < 336) ? f2b(W1[(size_t)k * 512 + n]) : (u16)0;
            return;
        }
        i -= 512 * 352;
        if (i < 512 * 512) {          // W2 [512,512] -> w2t [512,512] T
            int n = i >> 9, k = i & 511;
            w2t[i] = f2b(W2[(size_t)k * 512 + n]);
            return;
        }
        i -= 512 * 512;
        if (i < 128 * 512) {          // Wc1 [512,128] -> wc1t [128,512] T
            int n = i >> 9, k = i & 511;
            wc1t[i] = f2b(Wc1[(size_t)k * 128 + n]);
        }
    } break;
    case 30: gemm_dev(gA, gB, gC, gBias, gAs, gAd, asr, ads,
                      gM, gN, gK, gAct, As, Bs, red); break;
    case 31: agg_dev(rowptr, col, asr, ads, hAb, gBias, hbB, aux, NODES); break;
    case 14: {    // logits = z(=gA bf16)[N,128] @ Wc2[128,10] + bc2
        for (int i = t; i < 1280; i += 256) smf[i] = Wc2[i];
        if (t < 10) smf[1280 + t] = bc2[t];
        __syncthreads();
        int n = gid;
        if (n >= NODES) return;
        float acc[10];
        for (int c = 0; c < 10; c++) acc[c] = smf[1280 + c];
        const u16* zp = gA + (size_t)n * 128;
        for (int k = 0; k < 128; k++) {
            float f = b2f(zp[k]);
            const float* wr = &smf[k * 10];
            for (int c = 0; c < 10; c++) acc[c] += f * wr[c];
        }
        float* op = out + (size_t)n * 10;
        for (int c = 0; c < 10; c++) op[c] = acc[c];
    } break;
    }
}

extern "C" void kernel_launch(void* const* d_in, const int* in_sizes, int n_in,
                              void* d_out, int out_size, void* d_ws, size_t ws_size,
                              hipStream_t stream) {
    const float* x   = (const float*)d_in[0];
    const int*   ei  = (const int*)d_in[1];
    const float* W1  = (const float*)d_in[2];
    const float* as1 = (const float*)d_in[3];
    const float* ad1 = (const float*)d_in[4];
    const float* b1  = (const float*)d_in[5];
    const float* W2  = (const float*)d_in[6];
    const float* as2 = (const float*)d_in[7];
    const float* ad2 = (const float*)d_in[8];
    const float* b2  = (const float*)d_in[9];
    const float* Wc1 = (const float*)d_in[10];
    const float* bc1 = (const float*)d_in[11];
    const float* Wc2 = (const float*)d_in[12];
    const float* bc2 = (const float*)d_in[13];

    const int NODES = in_sizes[0] / 336;   // 50000
    const int E     = in_sizes[1] / 2;     // 500000

    char* ws = (char*)d_ws;
    size_t off = 0;
    auto alloc = [&](size_t b) -> char* {
        char* p = ws + off; off = (off + b + 255) & ~(size_t)255; return p;
    };
    u16*   xb   = (u16*)alloc((size_t)NODES * 352 * 2);   // reused as z later
    u16*   hAb  = (u16*)alloc((size_t)NODES * 512 * 2);   // GEMM out (bf16)
    u16*   hbB  = (u16*)alloc((size_t)NODES * 512 * 2);   // agg out (bf16)
    float* asr  = (float*)alloc((size_t)NODES * 4 * 4);
    float* ads  = (float*)alloc((size_t)NODES * 4 * 4);
    u16*   w1t  = (u16*)alloc((size_t)512 * 352 * 2);
    u16*   w2t  = (u16*)alloc((size_t)512 * 512 * 2);
    u16*   wc1t = (u16*)alloc((size_t)128 * 512 * 2);
    int* flag   = (int*)alloc(256);
    int* cnt    = (int*)alloc((size_t)NODES * 4);
    int* tmp    = (int*)alloc((size_t)NODES * 4);
    int* bsum   = (int*)alloc(4096);
    int* boff   = (int*)alloc(4096);
    int* rowptr = (int*)alloc((size_t)(NODES + 1) * 4);
    int* cursor = (int*)alloc((size_t)NODES * 4);
    int* col    = (int*)alloc((size_t)(E + NODES) * 4);
    u16* z      = xb;   // xb dead after GEMM1

    const int nblk = (NODES + 255) / 256;
    const int eblk = (E + NODES + 255) / 256;
    const int oblk = (out_size + 255) / 256;
    const int mt   = (NODES + 127) / 128;
    const int cvt_total = NODES * 352 + 512 * 352 + 512 * 512 + 128 * 512;

    auto L = [&](int phase, int aux, dim3 grid,
                 const u16* gA = nullptr, const u16* gB = nullptr,
                 u16* gC = nullptr, const float* gBias = nullptr,
                 const float* gAs = nullptr, const float* gAd = nullptr,
                 int gM = 0, int gN = 0, int gK = 0, int gAct = 0) {
        BaselineGAT_41764261987077_kernel<<<grid, 256, 0, stream>>>(
            phase, aux, x, ei, W1, as1, ad1, b1, W2, as2, ad2, b2,
            Wc1, bc1, Wc2, bc2, (float*)d_out,
            hAb, hbB, asr, ads, xb, w1t, w2t, wc1t,
            flag, cnt, tmp, bsum, boff, rowptr, cursor, col,
            gA, gB, gC, gBias, gAs, gAd, gM, gN, gK, gAct,
            NODES, E, nblk);
    };

    L(100, 0, oblk);                                    // tracer paint
    if (n_in < 14 || off > ws_size) { L(100, 1, oblk); return; }

    // CSR build (detect+zero merged)
    L(0, 0, nblk + 1);
    L(2, 0, eblk);
    L(3, 0, nblk);
    L(4, 0, 1);
    L(5, 0, nblk);
    L(6, 0, eblk);

    // bf16 conversions (single dispatch)
    L(20, 0, (cvt_total + 255) / 256);

    // layer 1: h1 = xb @ w1t^T (bf16) + fused alpha, agg(elu) -> hbB
    L(30, 0, dim3(mt, 4), xb, w1t, hAb, nullptr, as1, ad1, NODES, 512, 352, 0);
    L(31, 1, 1024, nullptr, nullptr, nullptr, b1);      // persistent-wave agg

    // layer 2
    L(30, 0, dim3(mt, 4), hbB, w2t, hAb, nullptr, as2, ad2, NODES, 512, 512, 0);
    L(31, 0, 1024, nullptr, nullptr, nullptr, b2);

    // classifier: z = relu(hbB @ wc1t^T + bc1) bf16, logits = z @ Wc2 + bc2
    L(30, 0, dim3(mt, 1), hbB, wc1t, z, bc1, nullptr, nullptr, NODES, 128, 512, 1);
    L(14, 0, nblk, z);
}

// Round 13
// 669.641 us; speedup vs baseline: 5.7541x; 1.1339x over previous
//
#include <hip/hip_runtime.h>
#include <math.h>

typedef unsigned short u16;
typedef unsigned int u32;
typedef short short8 __attribute__((ext_vector_type(8)));
typedef __bf16 bf16x8 __attribute__((ext_vector_type(8)));
typedef float f32x4 __attribute__((ext_vector_type(4)));

__device__ __forceinline__ float b2f(u16 u) {
    union { u32 i; float f; } v; v.i = ((u32)u) << 16; return v.f;
}
__device__ __forceinline__ float b2f_lo(u32 q) {
    union { u32 i; float f; } v; v.i = q << 16; return v.f;
}
__device__ __forceinline__ float b2f_hi(u32 q) {
    union { u32 i; float f; } v; v.i = q & 0xffff0000u; return v.f;
}
__device__ __forceinline__ u16 f2b(float f) {
    union { float f; u32 i; } v; v.f = f;
    u32 i = v.i;
    u32 r = (i + 0x7fffu + ((i >> 16) & 1u)) >> 16;   // RNE fp32 -> bf16
    return (u16)r;
}
__device__ __forceinline__ u32 pack2(u16 a, u16 b) { return (u32)a | ((u32)b << 16); }

// ---------- device helpers (all phases live in the ONE named kernel) ----------

// segment softmax + aggregate. Persistent waves; lane l owns channels 8l..8l+7
// (head = l>>4). No max-subtraction (|e| small -> exp fp32-safe; ratio exact).
// 4-way unrolled: four independent 16B gathers in flight.
__device__ void agg_dev(const int* __restrict__ rowptr, const int* __restrict__ col,
                        const float* __restrict__ asrc, const float* __restrict__ adst,
                        const u16* __restrict__ hb, const float* __restrict__ bias,
                        u16* __restrict__ outb, int elu, int NODES) {
    const int wid = (blockIdx.x * 256 + threadIdx.x) >> 6;
    const int nwaves = gridDim.x << 2;
    const int l = threadIdx.x & 63;
    const int hd = l >> 4;
    const int cbase = 8 * l;
    float bv[8];
#pragma unroll
    for (int c = 0; c < 8; c++) bv[c] = bias[cbase + c];

    for (int n = wid; n < NODES; n += nwaves) {
        int beg = rowptr[n], end = rowptr[n + 1];
        float ad = adst[n * 4 + hd];
        float acc0[8], acc1[8];
#pragma unroll
        for (int c = 0; c < 8; c++) { acc0[c] = 0.f; acc1[c] = 0.f; }
        float ss0 = 0.f, ss1 = 0.f;
        int j = beg;
        for (; j + 3 < end; j += 4) {
            int s0 = col[j], s1 = col[j + 1], s2 = col[j + 2], s3 = col[j + 3];
            const u32* hp0 = (const u32*)(hb + (size_t)s0 * 512 + cbase);
            const u32* hp1 = (const u32*)(hb + (size_t)s1 * 512 + cbase);
            const u32* hp2 = (const u32*)(hb + (size_t)s2 * 512 + cbase);
            const u32* hp3 = (const u32*)(hb + (size_t)s3 * 512 + cbase);
            u32 q00 = hp0[0], q01 = hp0[1], q02 = hp0[2], q03 = hp0[3];
            u32 q10 = hp1[0], q11 = hp1[1], q12 = hp1[2], q13 = hp1[3];
            u32 q20 = hp2[0], q21 = hp2[1], q22 = hp2[2], q23 = hp2[3];
            u32 q30 = hp3[0], q31 = hp3[1], q32 = hp3[2], q33 = hp3[3];
            float e0 = asrc[s0 * 4 + hd] + ad; e0 = e0 > 0.f ? e0 : 0.2f * e0;
            float e1 = asrc[s1 * 4 + hd] + ad; e1 = e1 > 0.f ? e1 : 0.2f * e1;
            float e2 = asrc[s2 * 4 + hd] + ad; e2 = e2 > 0.f ? e2 : 0.2f * e2;
            float e3 = asrc[s3 * 4 + hd] + ad; e3 = e3 > 0.f ? e3 : 0.2f * e3;
            float p0 = __expf(e0), p1 = __expf(e1), p2 = __expf(e2), p3 = __expf(e3);
            ss0 += p0 + p2; ss1 += p1 + p3;
            acc0[0] += p0 * b2f_lo(q00) + p2 * b2f_lo(q20);
            acc0[1] += p0 * b2f_hi(q00) + p2 * b2f_hi(q20);
            acc0[2] += p0 * b2f_lo(q01) + p2 * b2f_lo(q21);
            acc0[3] += p0 * b2f_hi(q01) + p2 * b2f_hi(q21);
            acc0[4] += p0 * b2f_lo(q02) + p2 * b2f_lo(q22);
            acc0[5] += p0 * b2f_hi(q02) + p2 * b2f_hi(q22);
            acc0[6] += p0 * b2f_lo(q03) + p2 * b2f_lo(q23);
            acc0[7] += p0 * b2f_hi(q03) + p2 * b2f_hi(q23);
            acc1[0] += p1 * b2f_lo(q10) + p3 * b2f_lo(q30);
            acc1[1] += p1 * b2f_hi(q10) + p3 * b2f_hi(q30);
            acc1[2] += p1 * b2f_lo(q11) + p3 * b2f_lo(q31);
            acc1[3] += p1 * b2f_hi(q11) + p3 * b2f_hi(q31);
            acc1[4] += p1 * b2f_lo(q12) + p3 * b2f_lo(q32);
            acc1[5] += p1 * b2f_hi(q12) + p3 * b2f_hi(q32);
            acc1[6] += p1 * b2f_lo(q13) + p3 * b2f_lo(q33);
            acc1[7] += p1 * b2f_hi(q13) + p3 * b2f_hi(q33);
        }
        for (; j < end; ++j) {
            int s0 = col[j];
            const u32* hp0 = (const u32*)(hb + (size_t)s0 * 512 + cbase);
            u32 q00 = hp0[0], q01 = hp0[1], q02 = hp0[2], q03 = hp0[3];
            float e0 = asrc[s0 * 4 + hd] + ad; e0 = e0 > 0.f ? e0 : 0.2f * e0;
            float p0 = __expf(e0);
            ss0 += p0;
            acc0[0] += p0 * b2f_lo(q00); acc0[1] += p0 * b2f_hi(q00);
            acc0[2] += p0 * b2f_lo(q01); acc0[3] += p0 * b2f_hi(q01);
            acc0[4] += p0 * b2f_lo(q02); acc0[5] += p0 * b2f_hi(q02);
            acc0[6] += p0 * b2f_lo(q03); acc0[7] += p0 * b2f_hi(q03);
        }
        float inv = 1.f / (ss0 + ss1 + 1e-16f);
        float v[8];
#pragma unroll
        for (int c = 0; c < 8; c++) {
            float tv = (acc0[c] + acc1[c]) * inv + bv[c];
            if (elu) tv = tv > 0.f ? tv : expm1f(tv);
            v[c] = tv;
        }
        u32* op = (u32*)(outb + (size_t)n * 512 + cbase);
        op[0] = pack2(f2b(v[0]), f2b(v[1]));
        op[1] = pack2(f2b(v[2]), f2b(v[3]));
        op[2] = pack2(f2b(v[4]), f2b(v[5]));
        op[3] = pack2(f2b(v[6]), f2b(v[7]));
    }
}

// MFMA GEMM: acc = A bf16[M,K] @ Bt bf16[N,K]^T, fp32 accum.
// 128x128 tile, 4 waves 2x2, register-staged LDS, K multiple of 32.
// act 0: store C bf16.  act 1: relu(+bias), store C bf16.
// act 2: relu(+bias), NO C store; fused logits: out[row,k] = z-row . Wc2 + bc2.
// aS != nullptr (with act 0): fused alpha epilogue (stores C too).
__device__ void gemm_dev(const u16* __restrict__ A, const u16* __restrict__ Bt,
                         u16* __restrict__ C, const float* __restrict__ bias,
                         const float* __restrict__ aS, const float* __restrict__ aD,
                         float* __restrict__ asr, float* __restrict__ ads,
                         const float* __restrict__ Wc2, const float* __restrict__ bc2,
                         float* __restrict__ outp,
                         int M, int N, int K, int act, char* shm,
                         u16* As, u16* Bs, float (*red)[128][2]) {
    const int t = threadIdx.x;
    const int l = t & 63, w = t >> 6;
    const int m0 = blockIdx.x * 128, n0 = blockIdx.y * 128;
    const int sr = t >> 2;             // 0..63
    const int sc = (t & 3) * 8;        // 16B chunks
    const int wm = (w >> 1) * 64, wn = (w & 1) * 64;

    const int rA0 = min(m0 + sr, M - 1);
    const int rA1 = min(m0 + sr + 64, M - 1);
    const int rB0 = min(n0 + sr, N - 1);
    const int rB1 = min(n0 + sr + 64, N - 1);

    f32x4 acc[4][4];
    f32x4 z4 = {0.f, 0.f, 0.f, 0.f};
#pragma unroll
    for (int i = 0; i < 4; i++)
#pragma unroll
        for (int j = 0; j < 4; j++) acc[i][j] = z4;

    for (int k0 = 0; k0 < K; k0 += 32) {
        short8 a0 = *(const short8*)(A + (size_t)rA0 * K + k0 + sc);
        short8 a1 = *(const short8*)(A + (size_t)rA1 * K + k0 + sc);
        short8 b0 = *(const short8*)(Bt + (size_t)rB0 * K + k0 + sc);
        short8 b1 = *(const short8*)(Bt + (size_t)rB1 * K + k0 + sc);
        __syncthreads();   // prior LDS reads done
        *(short8*)(As + sr * 32 + sc) = a0;
        *(short8*)(As + (sr + 64) * 32 + sc) = a1;
        *(short8*)(Bs + sr * 32 + sc) = b0;
        *(short8*)(Bs + (sr + 64) * 32 + sc) = b1;
        __syncthreads();

        bf16x8 af[4], bfr[4];
#pragma unroll
        for (int i = 0; i < 4; i++) {
            af[i]  = *(const bf16x8*)(As + (wm + i * 16 + (l & 15)) * 32 + (l >> 4) * 8);
            bfr[i] = *(const bf16x8*)(Bs + (wn + i * 16 + (l & 15)) * 32 + (l >> 4) * 8);
        }
#pragma unroll
        for (int i = 0; i < 4; i++)
#pragma unroll
            for (int j = 0; j < 4; j++)
                acc[i][j] = __builtin_amdgcn_mfma_f32_16x16x32_bf16(af[i], bfr[j], acc[i][j], 0, 0, 0);
    }

    if (act == 2) {
        // fused classifier epilogue: z = relu(acc + bias); logits = z . Wc2 + bc2
        __syncthreads();                       // done with As/Bs LDS
        float* wl = (float*)shm;               // 1280 floats Wc2 + 10 bc2
        float (*logbuf)[128][10] = (float (*)[128][10])(shm + 8192);  // 10240 B
        for (int i = t; i < 1280; i += 256) wl[i] = Wc2[i];
        if (t < 10) wl[1280 + t] = bc2[t];
        __syncthreads();
        float aSv[4];                          // per-j column index cache
        int cj[4];
#pragma unroll
        for (int j = 0; j < 4; j++) cj[j] = wn + j * 16 + (l & 15);
        (void)aSv;
#pragma unroll
        for (int i = 0; i < 4; i++) {
#pragma unroll
            for (int r = 0; r < 4; r++) {
                float zv[4];
#pragma unroll
                for (int j = 0; j < 4; j++) {
                    float v = acc[i][j][r] + (bias ? bias[cj[j]] : 0.f);
                    zv[j] = v > 0.f ? v : 0.f;
                }
                float part[10];
#pragma unroll
                for (int k = 0; k < 10; k++) {
                    float s = 0.f;
#pragma unroll
                    for (int j = 0; j < 4; j++) s += zv[j] * wl[cj[j] * 10 + k];
#pragma unroll
                    for (int o = 1; o < 16; o <<= 1) s += __shfl_xor(s, o);
                    part[k] = s;
                }
                if ((l & 15) == 0) {
                    int rl = wm + i * 16 + (l >> 4) * 4 + r;
#pragma unroll
                    for (int k = 0; k < 10; k++) logbuf[w & 1][rl][k] = part[k];
                }
            }
        }
        __syncthreads();
        if (t < 128) {
            int row = m0 + t;
            if (row < M) {
#pragma unroll
                for (int k = 0; k < 10; k++)
                    outp[(size_t)row * 10 + k] =
                        logbuf[0][t][k] + logbuf[1][t][k] + wl[1280 + k];
            }
        }
        return;
    }

#pragma unroll
    for (int i = 0; i < 4; i++) {
        int rbase = m0 + wm + i * 16 + (l >> 4) * 4;
#pragma unroll
        for (int j = 0; j < 4; j++) {
            int c = n0 + wn + j * 16 + (l & 15);
            float bv = bias ? bias[c] : 0.f;
#pragma unroll
            for (int r = 0; r < 4; r++) {
                int row = rbase + r;
                if (row < M) {
                    float v = acc[i][j][r] + bv;
                    if (act == 1) v = v > 0.f ? v : 0.f;
                    C[(size_t)row * N + c] = f2b(v);
                }
            }
        }
    }

    if (aS) {   // fused alpha epilogue; head hd = n0/128
        const int hd = n0 >> 7;
        float aSv[4], aDv[4];
#pragma unroll
        for (int j = 0; j < 4; j++) {
            int c = n0 + wn + j * 16 + (l & 15);
            aSv[j] = aS[c];
            aDv[j] = aD[c];
        }
#pragma unroll
        for (int i = 0; i < 4; i++) {
#pragma unroll
            for (int r = 0; r < 4; r++) {
                float vs = 0.f, vd = 0.f;
#pragma unroll
                for (int j = 0; j < 4; j++) {
                    float hv = acc[i][j][r];
                    vs += hv * aSv[j];
                    vd += hv * aDv[j];
                }
#pragma unroll
                for (int o = 1; o < 16; o <<= 1) {
                    vs += __shfl_xor(vs, o);
                    vd += __shfl_xor(vd, o);
                }
                if ((l & 15) == 0) {
                    int rl = wm + i * 16 + (l >> 4) * 4 + r;
                    red[w & 1][rl][0] = vs;
                    red[w & 1][rl][1] = vd;
                }
            }
        }
        __syncthreads();
        if (t < 128) {
            int row = m0 + t;
            if (row < M) {
                asr[row * 4 + hd] = red[0][t][0] + red[1][t][0];
                ads[row * 4 + hd] = red[0][t][1] + red[1][t][1];
            }
        }
    }
}

__global__ __launch_bounds__(256) void BaselineGAT_41764261987077_kernel(
    int phase, int aux,
    const float* x, const int* ei,
    const float* W1, const float* as1, const float* ad1, const float* b1,
    const float* W2, const float* as2, const float* ad2, const float* b2,
    const float* Wc1, const float* bc1, const float* Wc2, const float* bc2,
    float* out,
    u16* hAb, u16* hbB, float* asr, float* ads,
    u16* xb, u16* w1t, u16* w2t, u16* wc1t,
    int* flag, int* cnt, int* tmp, int* bsum, int* boff,
    int* rowptr, int* cursor, int* col,
    const u16* gA, const u16* gB, u16* gC, const float* gBias,
    const float* gAs, const float* gAd,
    int gM, int gN, int gK, int gAct,
    int NODES, int E, int nblk)
{
    // One aliased LDS arena (18.5 KB):
    // GEMM: As(8K)+Bs(8K)+red(2K); cls-fused: wl(5.2K)+logbuf(10.2K@8K); scans: smi.
    __shared__ f32x4 shm4[1156];   // 18496 B
    char* shm = (char*)shm4;
    u16* As = (u16*)shm;
    u16* Bs = (u16*)(shm + 8192);
    float (*red)[128][2] = (float (*)[128][2])(shm + 16384);
    float* smf = (float*)shm;
    int* smi = (int*)shm;

    const int t = threadIdx.x;
    const int gid = blockIdx.x * 256 + t;
    const int EN = E + NODES;

    switch (phase) {
    case 100: {   // tracer / ws-sentinel paint
        float v = (aux == 0) ? 0.25f : 1000.0f;
        if (gid < NODES * 10) out[gid] = v;
    } break;
    case 0: {     // block 0: edge dtype detect; other blocks: zero cnt
        if (blockIdx.x == 0) {
            if (t == 0) smi[256] = 0;
            __syncthreads();
            for (int j = t; j < 1024; j += 256)
                if (ei[2 * j + 1] != 0) atomicAdd(&smi[256], 1);
            __syncthreads();
            if (t == 0) flag[0] = (smi[256] < 16) ? 2 : 1;
        } else {
            int i = (blockIdx.x - 1) * 256 + t;
            if (i < NODES) cnt[i] = 0;
        }
    } break;
    case 2: {     // histogram of dst (+self loops)
        if (gid >= EN) return;
        int step = flag[0];
        int d;
        if (gid < E) {
            d = ei[(size_t)(E + gid) * step];
            if ((unsigned)d >= (unsigned)NODES) d = 0;
        } else d = gid - E;
        atomicAdd(&cnt[d], 1);
    } break;
    case 3: {     // block-local inclusive scan
        smi[t] = (gid < NODES) ? cnt[gid] : 0;
        __syncthreads();
        for (int o = 1; o < 256; o <<= 1) {
            int add = (t >= o) ? smi[t - o] : 0;
            __syncthreads();
            smi[t] += add;
            __syncthreads();
        }
        if (gid < NODES) tmp[gid] = smi[t];
        if (t == 255) bsum[blockIdx.x] = smi[255];
    } break;
    case 4: {
        if (blockIdx.x == 0 && t == 0) {
            int ex = 0;
            for (int b = 0; b < nblk; b++) { boff[b] = ex; ex += bsum[b]; }
        }
    } break;
    case 5: {
        if (gid >= NODES) return;
        int incl = tmp[gid] + boff[blockIdx.x];
        rowptr[gid + 1] = incl;
        cursor[gid] = incl - cnt[gid];
        if (gid == 0) rowptr[0] = 0;
    } break;
    case 6: {
        if (gid >= EN) return;
        int step = flag[0];
        int d, s;
        if (gid < E) {
            s = ei[(size_t)gid * step];
            d = ei[(size_t)(E + gid) * step];
            if ((unsigned)s >= (unsigned)NODES) s = 0;
            if ((unsigned)d >= (unsigned)NODES) d = 0;
        } else { d = gid - E; s = d; }
        int pos = atomicAdd(&cursor[d], 1);
        col[pos] = s;
    } break;
    case 20: {    // conversions: vectorized x (8 elems/thread) + scalar weights
        int i = gid;
        const int XC = NODES * 44;            // 8-elem chunks of xb rows (352/8)
        if (i < XC) {
            int n = i / 44, kk = (i - n * 44) * 8;
            short8 o;
            if (kk < 336) {
                const f32x4* xp = (const f32x4*)(x + (size_t)n * 336 + kk);
                f32x4 f0 = xp[0], f1 = xp[1];
                o[0] = (short)f2b(f0[0]); o[1] = (short)f2b(f0[1]);
                o[2] = (short)f2b(f0[2]); o[3] = (short)f2b(f0[3]);
                o[4] = (short)f2b(f1[0]); o[5] = (short)f2b(f1[1]);
                o[6] = (short)f2b(f1[2]); o[7] = (short)f2b(f1[3]);
            } else {
#pragma unroll
                for (int e = 0; e < 8; e++) o[e] = 0;
            }
            *(short8*)(xb + (size_t)n * 352 + kk) = o;
            return;
        }
        i -= XC;
        if (i < 512 * 352) {          // W1 [336,512] -> w1t [512,352] T+pad
            int n = i / 352, k = i - n * 352;
            w1t[i] = (k < 336) ? f2b(W1[(size_t)k * 512 + n]) : (u16)0;
            return;
        }
        i -= 512 * 352;
        if (i < 512 * 512) {          // W2 [512,512] -> w2t [512,512] T
            int n = i >> 9, k = i & 511;
            w2t[i] = f2b(W2[(size_t)k * 512 + n]);
            return;
        }
        i -= 512 * 512;
        if (i < 128 * 512) {          // Wc1 [512,128] -> wc1t [128,512] T
            int n = i >> 9, k = i & 511;
            wc1t[i] = f2b(Wc1[(size_t)k * 128 + n]);
        }
    } break;
    case 30: gemm_dev(gA, gB, gC, gBias, gAs, gAd, asr, ads,
                      Wc2, bc2, out, gM, gN, gK, gAct, shm, As, Bs, red); break;
    case 31: agg_dev(rowptr, col, asr, ads, hAb, gBias, hbB, aux, NODES); break;
    }
}

extern "C" void kernel_launch(void* const* d_in, const int* in_sizes, int n_in,
                              void* d_out, int out_size, void* d_ws, size_t ws_size,
                              hipStream_t stream) {
    const float* x   = (const float*)d_in[0];
    const int*   ei  = (const int*)d_in[1];
    const float* W1  = (const float*)d_in[2];
    const float* as1 = (const float*)d_in[3];
    const float* ad1 = (const float*)d_in[4];
    const float* b1  = (const float*)d_in[5];
    const float* W2  = (const float*)d_in[6];
    const float* as2 = (const float*)d_in[7];
    const float* ad2 = (const float*)d_in[8];
    const float* b2  = (const float*)d_in[9];
    const float* Wc1 = (const float*)d_in[10];
    const float* bc1 = (const float*)d_in[11];
    const float* Wc2 = (const float*)d_in[12];
    const float* bc2 = (const float*)d_in[13];

    const int NODES = in_sizes[0] / 336;   // 50000
    const int E     = in_sizes[1] / 2;     // 500000

    char* ws = (char*)d_ws;
    size_t off = 0;
    auto alloc = [&](size_t b) -> char* {
        char* p = ws + off; off = (off + b + 255) & ~(size_t)255; return p;
    };
    u16*   xb   = (u16*)alloc((size_t)NODES * 352 * 2);
    u16*   hAb  = (u16*)alloc((size_t)NODES * 512 * 2);   // GEMM out (bf16)
    u16*   hbB  = (u16*)alloc((size_t)NODES * 512 * 2);   // agg out (bf16)
    float* asr  = (float*)alloc((size_t)NODES * 4 * 4);
    float* ads  = (float*)alloc((size_t)NODES * 4 * 4);
    u16*   w1t  = (u16*)alloc((size_t)512 * 352 * 2);
    u16*   w2t  = (u16*)alloc((size_t)512 * 512 * 2);
    u16*   wc1t = (u16*)alloc((size_t)128 * 512 * 2);
    int* flag   = (int*)alloc(256);
    int* cnt    = (int*)alloc((size_t)NODES * 4);
    int* tmp    = (int*)alloc((size_t)NODES * 4);
    int* bsum   = (int*)alloc(4096);
    int* boff   = (int*)alloc(4096);
    int* rowptr = (int*)alloc((size_t)(NODES + 1) * 4);
    int* cursor = (int*)alloc((size_t)NODES * 4);
    int* col    = (int*)alloc((size_t)(E + NODES) * 4);

    const int nblk = (NODES + 255) / 256;
    const int eblk = (E + NODES + 255) / 256;
    const int oblk = (out_size + 255) / 256;
    const int mt   = (NODES + 127) / 128;
    const int cvt_total = NODES * 44 + 512 * 352 + 512 * 512 + 128 * 512;

    auto L = [&](int phase, int aux, dim3 grid,
                 const u16* gA = nullptr, const u16* gB = nullptr,
                 u16* gC = nullptr, const float* gBias = nullptr,
                 const float* gAs = nullptr, const float* gAd = nullptr,
                 int gM = 0, int gN = 0, int gK = 0, int gAct = 0) {
        BaselineGAT_41764261987077_kernel<<<grid, 256, 0, stream>>>(
            phase, aux, x, ei, W1, as1, ad1, b1, W2, as2, ad2, b2,
            Wc1, bc1, Wc2, bc2, (float*)d_out,
            hAb, hbB, asr, ads, xb, w1t, w2t, wc1t,
            flag, cnt, tmp, bsum, boff, rowptr, cursor, col,
            gA, gB, gC, gBias, gAs, gAd, gM, gN, gK, gAct,
            NODES, E, nblk);
    };

    L(100, 0, oblk);                                    // tracer paint
    if (n_in < 14 || off > ws_size) { L(100, 1, oblk); return; }

    // CSR build (detect+zero merged)
    L(0, 0, nblk + 1);
    L(2, 0, eblk);
    L(3, 0, nblk);
    L(4, 0, 1);
    L(5, 0, nblk);
    L(6, 0, eblk);

    // bf16 conversions (vectorized x path)
    L(20, 0, (cvt_total + 255) / 256);

    // layer 1: h1 = xb @ w1t^T (bf16) + fused alpha, agg(elu) -> hbB
    L(30, 0, dim3(mt, 4), xb, w1t, hAb, nullptr, as1, ad1, NODES, 512, 352, 0);
    L(31, 1, 1024, nullptr, nullptr, nullptr, b1);      // persistent-wave agg

    // layer 2
    L(30, 0, dim3(mt, 4), hbB, w2t, hAb, nullptr, as2, ad2, NODES, 512, 512, 0);
    L(31, 0, 1024, nullptr, nullptr, nullptr, b2);

    // classifier fused: relu(hbB @ wc1t^T + bc1) . Wc2 + bc2 -> out (fp32)
    L(30, 0, dim3(mt, 1), hbB, wc1t, nullptr, bc1, nullptr, nullptr, NODES, 128, 512, 2);
}

// Round 14
// 652.650 us; speedup vs baseline: 5.9040x; 1.0260x over previous
//
#include <hip/hip_runtime.h>
#include <math.h>

typedef unsigned short u16;
typedef unsigned int u32;
typedef short short8 __attribute__((ext_vector_type(8)));
typedef __bf16 bf16x8 __attribute__((ext_vector_type(8)));
typedef float f32x4 __attribute__((ext_vector_type(4)));
typedef u32 u32x4 __attribute__((ext_vector_type(4)));

__device__ __forceinline__ float b2f(u16 u) {
    union { u32 i; float f; } v; v.i = ((u32)u) << 16; return v.f;
}
__device__ __forceinline__ float b2f_lo(u32 q) {
    union { u32 i; float f; } v; v.i = q << 16; return v.f;
}
__device__ __forceinline__ float b2f_hi(u32 q) {
    union { u32 i; float f; } v; v.i = q & 0xffff0000u; return v.f;
}
__device__ __forceinline__ u16 f2b(float f) {
    union { float f; u32 i; } v; v.f = f;
    u32 i = v.i;
    u32 r = (i + 0x7fffu + ((i >> 16) & 1u)) >> 16;   // RNE fp32 -> bf16
    return (u16)r;
}
__device__ __forceinline__ u32 pack2(u16 a, u16 b) { return (u32)a | ((u32)b << 16); }

// ---------- device helpers (all phases live in the ONE named kernel) ----------

// segment softmax + aggregate. Persistent waves (grid 4096 blocks = 16K waves);
// lane l owns channels 8l..8l+7 (head = l>>4). No max-subtraction (|e| small).
// 4-way unrolled; one dwordx4 gather per lane per edge.
__device__ void agg_dev(const int* __restrict__ rowptr, const int* __restrict__ col,
                        const float* __restrict__ asrc, const float* __restrict__ adst,
                        const u16* __restrict__ hb, const float* __restrict__ bias,
                        u16* __restrict__ outb, int elu, int NODES) {
    const int wid = (blockIdx.x * 256 + threadIdx.x) >> 6;
    const int nwaves = gridDim.x << 2;
    const int l = threadIdx.x & 63;
    const int hd = l >> 4;
    const int cbase = 8 * l;
    float bv[8];
#pragma unroll
    for (int c = 0; c < 8; c++) bv[c] = bias[cbase + c];

    for (int n = wid; n < NODES; n += nwaves) {
        int beg = rowptr[n], end = rowptr[n + 1];
        float ad = adst[n * 4 + hd];
        float acc0[8], acc1[8];
#pragma unroll
        for (int c = 0; c < 8; c++) { acc0[c] = 0.f; acc1[c] = 0.f; }
        float ss0 = 0.f, ss1 = 0.f;
        int j = beg;
        for (; j + 3 < end; j += 4) {
            int s0 = col[j], s1 = col[j + 1], s2 = col[j + 2], s3 = col[j + 3];
            u32x4 q0 = *(const u32x4*)(hb + (size_t)s0 * 512 + cbase);
            u32x4 q1 = *(const u32x4*)(hb + (size_t)s1 * 512 + cbase);
            u32x4 q2 = *(const u32x4*)(hb + (size_t)s2 * 512 + cbase);
            u32x4 q3 = *(const u32x4*)(hb + (size_t)s3 * 512 + cbase);
            float e0 = asrc[s0 * 4 + hd] + ad; e0 = e0 > 0.f ? e0 : 0.2f * e0;
            float e1 = asrc[s1 * 4 + hd] + ad; e1 = e1 > 0.f ? e1 : 0.2f * e1;
            float e2 = asrc[s2 * 4 + hd] + ad; e2 = e2 > 0.f ? e2 : 0.2f * e2;
            float e3 = asrc[s3 * 4 + hd] + ad; e3 = e3 > 0.f ? e3 : 0.2f * e3;
            float p0 = __expf(e0), p1 = __expf(e1), p2 = __expf(e2), p3 = __expf(e3);
            ss0 += p0 + p2; ss1 += p1 + p3;
#pragma unroll
            for (int q = 0; q < 4; q++) {
                acc0[2 * q]     += p0 * b2f_lo(q0[q]) + p2 * b2f_lo(q2[q]);
                acc0[2 * q + 1] += p0 * b2f_hi(q0[q]) + p2 * b2f_hi(q2[q]);
                acc1[2 * q]     += p1 * b2f_lo(q1[q]) + p3 * b2f_lo(q3[q]);
                acc1[2 * q + 1] += p1 * b2f_hi(q1[q]) + p3 * b2f_hi(q3[q]);
            }
        }
        for (; j < end; ++j) {
            int s0 = col[j];
            u32x4 q0 = *(const u32x4*)(hb + (size_t)s0 * 512 + cbase);
            float e0 = asrc[s0 * 4 + hd] + ad; e0 = e0 > 0.f ? e0 : 0.2f * e0;
            float p0 = __expf(e0);
            ss0 += p0;
#pragma unroll
            for (int q = 0; q < 4; q++) {
                acc0[2 * q]     += p0 * b2f_lo(q0[q]);
                acc0[2 * q + 1] += p0 * b2f_hi(q0[q]);
            }
        }
        float inv = 1.f / (ss0 + ss1 + 1e-16f);
        float v[8];
#pragma unroll
        for (int c = 0; c < 8; c++) {
            float tv = (acc0[c] + acc1[c]) * inv + bv[c];
            if (elu) tv = tv > 0.f ? tv : expm1f(tv);
            v[c] = tv;
        }
        u32* op = (u32*)(outb + (size_t)n * 512 + cbase);
        op[0] = pack2(f2b(v[0]), f2b(v[1]));
        op[1] = pack2(f2b(v[2]), f2b(v[3]));
        op[2] = pack2(f2b(v[4]), f2b(v[5]));
        op[3] = pack2(f2b(v[6]), f2b(v[7]));
    }
}

// MFMA GEMM: acc = A bf16[M,K] @ Bt bf16[N,K]^T, fp32 accum.
// 128x128 tile, 4 waves 2x2, register-staged LDS, K multiple of 32.
// act 0: store C bf16.  act 1: relu(+bias), store C bf16.
// act 2: relu(+bias), NO C store; fused logits: out[row,k] = z-row . Wc2 + bc2.
// aS != nullptr (with act 0): fused alpha epilogue (stores C too).
__device__ void gemm_dev(const u16* __restrict__ A, const u16* __restrict__ Bt,
                         u16* __restrict__ C, const float* __restrict__ bias,
                         const float* __restrict__ aS, const float* __restrict__ aD,
                         float* __restrict__ asr, float* __restrict__ ads,
                         const float* __restrict__ Wc2, const float* __restrict__ bc2,
                         float* __restrict__ outp,
                         int M, int N, int K, int act, char* shm,
                         u16* As, u16* Bs, float (*red)[128][2]) {
    const int t = threadIdx.x;
    const int l = t & 63, w = t >> 6;
    const int m0 = blockIdx.x * 128, n0 = blockIdx.y * 128;
    const int sr = t >> 2;             // 0..63
    const int sc = (t & 3) * 8;        // 16B chunks
    const int wm = (w >> 1) * 64, wn = (w & 1) * 64;

    const int rA0 = min(m0 + sr, M - 1);
    const int rA1 = min(m0 + sr + 64, M - 1);
    const int rB0 = min(n0 + sr, N - 1);
    const int rB1 = min(n0 + sr + 64, N - 1);

    f32x4 acc[4][4];
    f32x4 z4 = {0.f, 0.f, 0.f, 0.f};
#pragma unroll
    for (int i = 0; i < 4; i++)
#pragma unroll
        for (int j = 0; j < 4; j++) acc[i][j] = z4;

    for (int k0 = 0; k0 < K; k0 += 32) {
        short8 a0 = *(const short8*)(A + (size_t)rA0 * K + k0 + sc);
        short8 a1 = *(const short8*)(A + (size_t)rA1 * K + k0 + sc);
        short8 b0 = *(const short8*)(Bt + (size_t)rB0 * K + k0 + sc);
        short8 b1 = *(const short8*)(Bt + (size_t)rB1 * K + k0 + sc);
        __syncthreads();   // prior LDS reads done
        *(short8*)(As + sr * 32 + sc) = a0;
        *(short8*)(As + (sr + 64) * 32 + sc) = a1;
        *(short8*)(Bs + sr * 32 + sc) = b0;
        *(short8*)(Bs + (sr + 64) * 32 + sc) = b1;
        __syncthreads();

        bf16x8 af[4], bfr[4];
#pragma unroll
        for (int i = 0; i < 4; i++) {
            af[i]  = *(const bf16x8*)(As + (wm + i * 16 + (l & 15)) * 32 + (l >> 4) * 8);
            bfr[i] = *(const bf16x8*)(Bs + (wn + i * 16 + (l & 15)) * 32 + (l >> 4) * 8);
        }
#pragma unroll
        for (int i = 0; i < 4; i++)
#pragma unroll
            for (int j = 0; j < 4; j++)
                acc[i][j] = __builtin_amdgcn_mfma_f32_16x16x32_bf16(af[i], bfr[j], acc[i][j], 0, 0, 0);
    }

    if (act == 2) {
        // fused classifier epilogue: z = relu(acc + bias); logits = z . Wc2 + bc2
        __syncthreads();                       // done with As/Bs LDS
        float* wl = (float*)shm;               // 1280 floats Wc2 + 10 bc2
        float (*logbuf)[128][10] = (float (*)[128][10])(shm + 8192);  // 10240 B
        for (int i = t; i < 1280; i += 256) wl[i] = Wc2[i];
        if (t < 10) wl[1280 + t] = bc2[t];
        __syncthreads();
        int cj[4];
#pragma unroll
        for (int j = 0; j < 4; j++) cj[j] = wn + j * 16 + (l & 15);
#pragma unroll
        for (int i = 0; i < 4; i++) {
#pragma unroll
            for (int r = 0; r < 4; r++) {
                float zv[4];
#pragma unroll
                for (int j = 0; j < 4; j++) {
                    float v = acc[i][j][r] + (bias ? bias[cj[j]] : 0.f);
                    zv[j] = v > 0.f ? v : 0.f;
                }
                float part[10];
#pragma unroll
                for (int k = 0; k < 10; k++) {
                    float s = 0.f;
#pragma unroll
                    for (int j = 0; j < 4; j++) s += zv[j] * wl[cj[j] * 10 + k];
#pragma unroll
                    for (int o = 1; o < 16; o <<= 1) s += __shfl_xor(s, o);
                    part[k] = s;
                }
                if ((l & 15) == 0) {
                    int rl = wm + i * 16 + (l >> 4) * 4 + r;
#pragma unroll
                    for (int k = 0; k < 10; k++) logbuf[w & 1][rl][k] = part[k];
                }
            }
        }
        __syncthreads();
        if (t < 128) {
            int row = m0 + t;
            if (row < M) {
#pragma unroll
                for (int k = 0; k < 10; k++)
                    outp[(size_t)row * 10 + k] =
                        logbuf[0][t][k] + logbuf[1][t][k] + wl[1280 + k];
            }
        }
        return;
    }

#pragma unroll
    for (int i = 0; i < 4; i++) {
        int rbase = m0 + wm + i * 16 + (l >> 4) * 4;
#pragma unroll
        for (int j = 0; j < 4; j++) {
            int c = n0 + wn + j * 16 + (l & 15);
            float bv = bias ? bias[c] : 0.f;
#pragma unroll
            for (int r = 0; r < 4; r++) {
                int row = rbase + r;
                if (row < M) {
                    float v = acc[i][j][r] + bv;
                    if (act == 1) v = v > 0.f ? v : 0.f;
                    C[(size_t)row * N + c] = f2b(v);
                }
            }
        }
    }

    if (aS) {   // fused alpha epilogue; head hd = n0/128
        const int hd = n0 >> 7;
        float aSv[4], aDv[4];
#pragma unroll
        for (int j = 0; j < 4; j++) {
            int c = n0 + wn + j * 16 + (l & 15);
            aSv[j] = aS[c];
            aDv[j] = aD[c];
        }
#pragma unroll
        for (int i = 0; i < 4; i++) {
#pragma unroll
            for (int r = 0; r < 4; r++) {
                float vs = 0.f, vd = 0.f;
#pragma unroll
                for (int j = 0; j < 4; j++) {
                    float hv = acc[i][j][r];
                    vs += hv * aSv[j];
                    vd += hv * aDv[j];
                }
#pragma unroll
                for (int o = 1; o < 16; o <<= 1) {
                    vs += __shfl_xor(vs, o);
                    vd += __shfl_xor(vd, o);
                }
                if ((l & 15) == 0) {
                    int rl = wm + i * 16 + (l >> 4) * 4 + r;
                    red[w & 1][rl][0] = vs;
                    red[w & 1][rl][1] = vd;
                }
            }
        }
        __syncthreads();
        if (t < 128) {
            int row = m0 + t;
            if (row < M) {
                asr[row * 4 + hd] = red[0][t][0] + red[1][t][0];
                ads[row * 4 + hd] = red[0][t][1] + red[1][t][1];
            }
        }
    }
}

__global__ __launch_bounds__(256) void BaselineGAT_41764261987077_kernel(
    int phase, int aux,
    const float* x, const int* ei,
    const float* W1, const float* as1, const float* ad1, const float* b1,
    const float* W2, const float* as2, const float* ad2, const float* b2,
    const float* Wc1, const float* bc1, const float* Wc2, const float* bc2,
    float* out,
    u16* hAb, u16* hbB, float* asr, float* ads,
    u16* xb, u16* w1t, u16* w2t, u16* wc1t,
    int* flag, int* cnt, int* tmp, int* bsum, int* boff,
    int* rowptr, int* cursor, int* col,
    const u16* gA, const u16* gB, u16* gC, const float* gBias,
    const float* gAs, const float* gAd,
    int gM, int gN, int gK, int gAct,
    int NODES, int E, int nblk)
{
    // One aliased LDS arena (18.5 KB).
    __shared__ f32x4 shm4[1156];   // 18496 B
    char* shm = (char*)shm4;
    u16* As = (u16*)shm;
    u16* Bs = (u16*)(shm + 8192);
    float (*red)[128][2] = (float (*)[128][2])(shm + 16384);
    int* smi = (int*)shm;
    int* smb = (int*)(shm + 2048);   // second scan buffer (lookback)

    const int t = threadIdx.x;
    const int gid = blockIdx.x * 256 + t;
    const int EN = E + NODES;

    switch (phase) {
    case 100: {   // ws-sentinel paint only
        if (gid < NODES * 10) out[gid] = 1000.0f;
    } break;
    case 0: {     // block 0: edge dtype detect; other blocks: zero cnt
        if (blockIdx.x == 0) {
            if (t == 0) smi[256] = 0;
            __syncthreads();
            for (int j = t; j < 1024; j += 256)
                if (ei[2 * j + 1] != 0) atomicAdd(&smi[256], 1);
            __syncthreads();
            if (t == 0) flag[0] = (smi[256] < 16) ? 2 : 1;
        } else {
            int i = (blockIdx.x - 1) * 256 + t;
            if (i < NODES) cnt[i] = 0;
        }
    } break;
    case 2: {     // histogram of dst (+self loops)
        if (gid >= EN) return;
        int step = flag[0];
        int d;
        if (gid < E) {
            d = ei[(size_t)(E + gid) * step];
            if ((unsigned)d >= (unsigned)NODES) d = 0;
        } else d = gid - E;
        atomicAdd(&cnt[d], 1);
    } break;
    case 3: {     // block-local inclusive scan
        smi[t] = (gid < NODES) ? cnt[gid] : 0;
        __syncthreads();
        for (int o = 1; o < 256; o <<= 1) {
            int add = (t >= o) ? smi[t - o] : 0;
            __syncthreads();
            smi[t] += add;
            __syncthreads();
        }
        if (gid < NODES) tmp[gid] = smi[t];
        if (t == 255) bsum[blockIdx.x] = smi[255];
    } break;
    case 5: {     // rowptr + cursor, with inline lookback scan of bsum
        smb[t] = (t < nblk) ? bsum[t] : 0;
        __syncthreads();
        for (int o = 1; o < 256; o <<= 1) {
            int add = (t >= o) ? smb[t - o] : 0;
            __syncthreads();
            smb[t] += add;
            __syncthreads();
        }
        int base = (blockIdx.x == 0) ? 0 : smb[blockIdx.x - 1];
        if (gid >= NODES) return;
        int incl = tmp[gid] + base;
        rowptr[gid + 1] = incl;
        cursor[gid] = incl - cnt[gid];
        if (gid == 0) rowptr[0] = 0;
    } break;
    case 6: {
        if (gid >= EN) return;
        int step = flag[0];
        int d, s;
        if (gid < E) {
            s = ei[(size_t)gid * step];
            d = ei[(size_t)(E + gid) * step];
            if ((unsigned)s >= (unsigned)NODES) s = 0;
            if ((unsigned)d >= (unsigned)NODES) d = 0;
        } else { d = gid - E; s = d; }
        int pos = atomicAdd(&cursor[d], 1);
        col[pos] = s;
    } break;
    case 20: {    // conversions: vectorized x (8 elems/thread) + scalar weights
        int i = gid;
        const int XC = NODES * 44;            // 8-elem chunks of xb rows (352/8)
        if (i < XC) {
            int n = i / 44, kk = (i - n * 44) * 8;
            short8 o;
            if (kk < 336) {
                const f32x4* xp = (const f32x4*)(x + (size_t)n * 336 + kk);
                f32x4 f0 = xp[0], f1 = xp[1];
                o[0] = (short)f2b(f0[0]); o[1] = (short)f2b(f0[1]);
                o[2] = (short)f2b(f0[2]); o[3] = (short)f2b(f0[3]);
                o[4] = (short)f2b(f1[0]); o[5] = (short)f2b(f1[1]);
                o[6] = (short)f2b(f1[2]); o[7] = (short)f2b(f1[3]);
            } else {
#pragma unroll
                for (int e = 0; e < 8; e++) o[e] = 0;
            }
            *(short8*)(xb + (size_t)n * 352 + kk) = o;
            return;
        }
        i -= XC;
        if (i < 512 * 352) {          // W1 [336,512] -> w1t [512,352] T+pad
            int n = i / 352, k = i - n * 352;
            w1t[i] = (k < 336) ? f2b(W1[(size_t)k * 512 + n]) : (u16)0;
            return;
        }
        i -= 512 * 352;
        if (i < 512 * 512) {          // W2 [512,512] -> w2t [512,512] T
            int n = i >> 9, k = i & 511;
            w2t[i] = f2b(W2[(size_t)k * 512 + n]);
            return;
        }
        i -= 512 * 512;
        if (i < 128 * 512) {          // Wc1 [512,128] -> wc1t [128,512] T
            int n = i >> 9, k = i & 511;
            wc1t[i] = f2b(Wc1[(size_t)k * 128 + n]);
        }
    } break;
    case 30: gemm_dev(gA, gB, gC, gBias, gAs, gAd, asr, ads,
                      Wc2, bc2, out, gM, gN, gK, gAct, shm, As, Bs, red); break;
    case 31: agg_dev(rowptr, col, asr, ads, hAb, gBias, hbB, aux, NODES); break;
    }
}

extern "C" void kernel_launch(void* const* d_in, const int* in_sizes, int n_in,
                              void* d_out, int out_size, void* d_ws, size_t ws_size,
                              hipStream_t stream) {
    const float* x   = (const float*)d_in[0];
    const int*   ei  = (const int*)d_in[1];
    const float* W1  = (const float*)d_in[2];
    const float* as1 = (const float*)d_in[3];
    const float* ad1 = (const float*)d_in[4];
    const float* b1  = (const float*)d_in[5];
    const float* W2  = (const float*)d_in[6];
    const float* as2 = (const float*)d_in[7];
    const float* ad2 = (const float*)d_in[8];
    const float* b2  = (const float*)d_in[9];
    const float* Wc1 = (const float*)d_in[10];
    const float* bc1 = (const float*)d_in[11];
    const float* Wc2 = (const float*)d_in[12];
    const float* bc2 = (const float*)d_in[13];

    const int NODES = in_sizes[0] / 336;   // 50000
    const int E     = in_sizes[1] / 2;     // 500000

    char* ws = (char*)d_ws;
    size_t off = 0;
    auto alloc = [&](size_t b) -> char* {
        char* p = ws + off; off = (off + b + 255) & ~(size_t)255; return p;
    };
    u16*   xb   = (u16*)alloc((size_t)NODES * 352 * 2);
    u16*   hAb  = (u16*)alloc((size_t)NODES * 512 * 2);   // GEMM out (bf16)
    u16*   hbB  = (u16*)alloc((size_t)NODES * 512 * 2);   // agg out (bf16)
    float* asr  = (float*)alloc((size_t)NODES * 4 * 4);
    float* ads  = (float*)alloc((size_t)NODES * 4 * 4);
    u16*   w1t  = (u16*)alloc((size_t)512 * 352 * 2);
    u16*   w2t  = (u16*)alloc((size_t)512 * 512 * 2);
    u16*   wc1t = (u16*)alloc((size_t)128 * 512 * 2);
    int* flag   = (int*)alloc(256);
    int* cnt    = (int*)alloc((size_t)NODES * 4);
    int* tmp    = (int*)alloc((size_t)NODES * 4);
    int* bsum   = (int*)alloc(4096);
    int* boff   = (int*)alloc(4096);
    int* rowptr = (int*)alloc((size_t)(NODES + 1) * 4);
    int* cursor = (int*)alloc((size_t)NODES * 4);
    int* col    = (int*)alloc((size_t)(E + NODES) * 4);

    const int nblk = (NODES + 255) / 256;
    const int eblk = (E + NODES + 255) / 256;
    const int oblk = (out_size + 255) / 256;
    const int mt   = (NODES + 127) / 128;
    const int cvt_total = NODES * 44 + 512 * 352 + 512 * 512 + 128 * 512;

    auto L = [&](int phase, int aux, dim3 grid,
                 const u16* gA = nullptr, const u16* gB = nullptr,
                 u16* gC = nullptr, const float* gBias = nullptr,
                 const float* gAs = nullptr, const float* gAd = nullptr,
                 int gM = 0, int gN = 0, int gK = 0, int gAct = 0) {
        BaselineGAT_41764261987077_kernel<<<grid, 256, 0, stream>>>(
            phase, aux, x, ei, W1, as1, ad1, b1, W2, as2, ad2, b2,
            Wc1, bc1, Wc2, bc2, (float*)d_out,
            hAb, hbB, asr, ads, xb, w1t, w2t, wc1t,
            flag, cnt, tmp, bsum, boff, rowptr, cursor, col,
            gA, gB, gC, gBias, gAs, gAd, gM, gN, gK, gAct,
            NODES, E, nblk);
    };

    if (n_in < 14 || off > ws_size) { L(100, 1, oblk); return; }

    // CSR build (detect+zero merged; scan2 folded into phase 5 lookback)
    L(0, 0, nblk + 1);
    L(2, 0, eblk);
    L(3, 0, nblk);
    L(5, 0, nblk);
    L(6, 0, eblk);

    // bf16 conversions (vectorized x path)
    L(20, 0, (cvt_total + 255) / 256);

    // layer 1: h1 = xb @ w1t^T (bf16) + fused alpha, agg(elu) -> hbB
    L(30, 0, dim3(mt, 4), xb, w1t, hAb, nullptr, as1, ad1, NODES, 512, 352, 0);
    L(31, 1, 4096, nullptr, nullptr, nullptr, b1);      // persistent-wave agg

    // layer 2
    L(30, 0, dim3(mt, 4), hbB, w2t, hAb, nullptr, as2, ad2, NODES, 512, 512, 0);
    L(31, 0, 4096, nullptr, nullptr, nullptr, b2);

    // classifier fused: relu(hbB @ wc1t^T + bc1) . Wc2 + bc2 -> out (fp32)
    L(30, 0, dim3(mt, 1), hbB, wc1t, nullptr, bc1, nullptr, nullptr, NODES, 128, 512, 2);
}